// Round 8
// baseline (168.271 us; speedup 1.0000x reference)
//
#include <hip/hip_runtime.h>

typedef __attribute__((ext_vector_type(4))) float f32x4;
typedef __attribute__((ext_vector_type(8))) short bf16x8;
typedef unsigned short u16;
typedef unsigned int u32;

#define LAMBDA_INIT 0.7836057665311429f
#define ONE_MINUS_LI 0.2163942334688571f
#define QSCALE_LOG2 0.1803368801111137f   // 0.125 * log2(e)

__device__ __forceinline__ u16 f2b(float f){
  union { float f; unsigned u; } v; v.f = f;
  unsigned r = v.u + 0x7fff + ((v.u >> 16) & 1);   // RNE
  return (u16)(r >> 16);
}

__device__ __forceinline__ f32x4 mfma16(bf16x8 a, bf16x8 b, f32x4 c){
  return __builtin_amdgcn_mfma_f32_16x16x32_bf16(a, b, c, 0, 0, 0);
}

// raw v_exp_f32 (2^x) — avoids OCML denorm-fixup libcall.
// NOTE: input must be a compiler-generated VALU result, NOT a raw MFMA dest
// (round-6 failure: asm reading MFMA dest directly -> hazard/garbage).
__device__ __forceinline__ float exp2_raw(float x){
  float r;
  asm("v_exp_f32 %0, %1" : "=v"(r) : "v"(x));
  return r;
}

// async global->LDS, 16B per lane; LDS dest = wave-uniform base + lane*16
__device__ __forceinline__ void async16(void* lds, const void* g){
  __builtin_amdgcn_global_load_lds((const __attribute__((address_space(1))) void*)g,
                                   (__attribute__((address_space(3))) void*)lds, 16, 0, 0);
}

// ---------------- convert fp32 -> bf16 (vectorized) ----------------
__global__ void cvt_kernel(const float4* __restrict__ in, ushort4* __restrict__ out, int n4){
  int i = blockIdx.x * blockDim.x + threadIdx.x;
  if (i < n4){
    float4 f = in[i];
    ushort4 o; o.x = f2b(f.x); o.y = f2b(f.y); o.z = f2b(f.z); o.w = f2b(f.w);
    out[i] = o;
  }
}

// ---------------- fused 4-weight transpose fp32[1024][1024] -> bf16[col][row] ----------------
__global__ void wtrans(const float* __restrict__ Wq, const float* __restrict__ Wk,
                       const float* __restrict__ Wv, const float* __restrict__ Wo,
                       u16* __restrict__ Wqkvt, u16* __restrict__ Wot){
  __shared__ float t[32][33];
  int z = blockIdx.z;
  const float* in = (z == 0) ? Wq : (z == 1) ? Wk : (z == 2) ? Wv : Wo;
  u16* out = (z < 3) ? (Wqkvt + (size_t)z * 1048576) : Wot;
  int c0 = blockIdx.x * 32, r0 = blockIdx.y * 32;
  int tx = threadIdx.x, ty = threadIdx.y;
  for (int i = 0; i < 32; i += 8) t[ty + i][tx] = in[(size_t)(r0 + ty + i) * 1024 + c0 + tx];
  __syncthreads();
  for (int i = 0; i < 32; i += 8) out[(size_t)(c0 + ty + i) * 1024 + r0 + tx] = f2b(t[tx][ty + i]);
}

// -------- transpose bf16[R][C] -> bf16[C][R], batched z --------
// PERM: key-tile permutation pi within each 64-chunk of the output row
// (pi(k)=32*(n>>1)+8*g+4*(n&1)+r for k=16n+4g+r) THEN the 8-elem XOR chunk swizzle.
template<int PERM>
__global__ void transpose_bf16(const u16* __restrict__ in, u16* __restrict__ out, int R, int C){
  __shared__ u16 t[32][34];
  int c0 = blockIdx.x * 32, r0 = blockIdx.y * 32;
  size_t boff = (size_t)blockIdx.z * R * C;
  int tx = threadIdx.x, ty = threadIdx.y;
  for (int i = 0; i < 32; i += 8) t[ty + i][tx] = in[boff + (size_t)(r0 + ty + i) * C + c0 + tx];
  __syncthreads();
  for (int i = 0; i < 32; i += 8){
    int dv = c0 + ty + i, s = r0 + tx;
    int sx;
    if (PERM){
      int sl = s & 63;
      int n = sl >> 4, g = (sl >> 2) & 3, r = sl & 3;
      int pos = (s & ~63) | ((n >> 1) << 5) | (g << 3) | ((n & 1) << 2) | r;
      sx = (pos & ~63) | ((((pos >> 3) & 7) ^ (dv & 7)) << 3) | (pos & 7);
    } else sx = s;
    out[boff + (size_t)dv * R + sx] = t[tx][ty + i];
  }
}

// ---------------- async double-buffered GEMM: C(MxN) = A * Bt^T ----------------
// 128 x BN tile, BK=64, global_load_lds staging (linear LDS, inverse-swizzled source,
// swizzled frag reads), counted-vmcnt pipeline, bijective XCD block swizzle (m-fast).
// EPI=0: fp32 C. EPI=1: fused QKV epilogue (proj = n0>>10; Q scaled log2-domain,
// K chunk-swizzled, V coalesced token-major — transposed by a separate kernel).
template<int BN, int EPI>
__global__ __launch_bounds__(256, 2) void gemm_async(
    const u16* __restrict__ A, const u16* __restrict__ Bt, float* __restrict__ Cp,
    u16* __restrict__ Qo, u16* __restrict__ Ko, u16* __restrict__ Vo,
    int M, int N, int K, int gm){
  constexpr int BCH = BN / 32;              // B 16B-chunks per thread per K-step
  __shared__ u16 As[2][128 * 64];
  __shared__ u16 Bs[2][BN * 64];
  int tid = threadIdx.x, w = tid >> 6, lane = tid & 63;
  int l16 = lane & 15, grp = lane >> 4;
  int wr = w >> 1, wc = w & 1;
  int nwg = gridDim.x, bid = blockIdx.x;
  int idx = (bid & 7) * (nwg >> 3) + (bid >> 3);
  int m0 = (idx & (gm - 1)) * 128, n0 = (idx / gm) * BN;

  int sr = lane >> 3;                        // == row&7 for every staged chunk
  int sc = ((lane & 7) ^ sr) << 3;           // inverse-swizzled source col (elems)
  const u16* pA = A  + (size_t)(m0 + w * 8 + sr) * K + sc;
  const u16* pB = Bt + (size_t)(n0 + w * 8 + sr) * K + sc;

  f32x4 acc[4][BN / 32] = {};

#define STAGEG(bb, k0) do{                                             \
    _Pragma("unroll")                                                  \
    for (int i = 0; i < 4; i++)                                        \
      async16(&As[bb][i * 2048 + w * 512], pA + (k0) + (size_t)i * 32 * K); \
    _Pragma("unroll")                                                  \
    for (int i = 0; i < BCH; i++)                                      \
      async16(&Bs[bb][i * 2048 + w * 512], pB + (k0) + (size_t)i * 32 * K); \
  } while(0)

  STAGEG(0, 0);
  int niter = K >> 6;
  for (int kt = 0; kt < niter; kt++){
    int cur = kt & 1;
    if (kt < niter - 1){
      STAGEG(cur ^ 1, (kt + 1) << 6);
      if constexpr (BN == 128) asm volatile("s_waitcnt vmcnt(8)" ::: "memory");
      else                     asm volatile("s_waitcnt vmcnt(6)" ::: "memory");
    } else {
      asm volatile("s_waitcnt vmcnt(0)" ::: "memory");
    }
    __builtin_amdgcn_s_barrier();

    const u16* Ap = As[cur];
    const u16* Bp = Bs[cur];
    #pragma unroll
    for (int kk = 0; kk < 2; kk++){
      bf16x8 a[4], b[BN / 32];
      #pragma unroll
      for (int m = 0; m < 4; m++){
        int r = wr * 64 + m * 16 + l16;
        a[m] = *(const bf16x8*)&Ap[r * 64 + (((kk * 4 + grp) ^ (r & 7)) << 3)];
      }
      #pragma unroll
      for (int n = 0; n < BCH; n++){
        int r = wc * (BN / 2) + n * 16 + l16;
        b[n] = *(const bf16x8*)&Bp[r * 64 + (((kk * 4 + grp) ^ (r & 7)) << 3)];
      }
      #pragma unroll
      for (int m = 0; m < 4; m++)
        #pragma unroll
        for (int n = 0; n < BCH; n++)
          acc[m][n] = mfma16(a[m], b[n], acc[m][n]);
    }
    if (kt < niter - 1){
      asm volatile("s_waitcnt lgkmcnt(0)" ::: "memory");
      __builtin_amdgcn_s_barrier();
    }
  }
#undef STAGEG

  if constexpr (EPI == 0){
    #pragma unroll
    for (int m = 0; m < 4; m++)
      #pragma unroll
      for (int n = 0; n < BCH; n++)
        #pragma unroll
        for (int r = 0; r < 4; r++)
          Cp[(size_t)(m0 + wr * 64 + m * 16 + grp * 4 + r) * N + n0 + wc * (BN / 2) + n * 16 + l16]
            = acc[m][n][r];
  } else {
    int proj = n0 >> 10;                     // block-uniform (BN=128 divides 1024)
    #pragma unroll
    for (int m = 0; m < 4; m++){
      int row = m0 + wr * 64 + m * 16 + grp * 4;
      #pragma unroll
      for (int n = 0; n < BCH; n++){
        int col = n0 + wc * (BN / 2) + n * 16 + l16;
        int cn = col & 1023;
        if (proj == 0){
          #pragma unroll
          for (int r = 0; r < 4; r++)
            Qo[(size_t)(row + r) * 1024 + cn] = f2b(acc[m][n][r] * QSCALE_LOG2);
        } else if (proj == 1){
          #pragma unroll
          for (int r = 0; r < 4; r++){
            int cs = (cn & ~63) | ((((cn >> 3) & 7) ^ ((row + r) & 7)) << 3) | (cn & 7);
            Ko[(size_t)(row + r) * 1024 + cs] = f2b(acc[m][n][r]);
          }
        } else {
          #pragma unroll
          for (int r = 0; r < 4; r++)
            Vo[(size_t)(row + r) * 1024 + cn] = f2b(acc[m][n][r]);
        }
      }
    }
  }
}

// ---------------- differential flash attention ----------------
// 32 q-rows per wave (2 groups of 16): each LDS K/V fragment read feeds 2x MFMAs,
// halving LDS read traffic per CU (the round-7 bottleneck). grid 256 = 1 block/CU,
// 128 q-rows/block. VGPR-heavy (~300) -> 1 wave/SIMD, launch_bounds(256,1).
// Fixed-shift softmax p = 2^(s-4); row-sum l via all-ones MFMA column.
__global__ __launch_bounds__(256, 1) void diff_attn(
    const u16* __restrict__ Qb, const u16* __restrict__ Kb, const u16* __restrict__ Vt,
    const float* __restrict__ lq1, const float* __restrict__ lk1,
    const float* __restrict__ lq2, const float* __restrict__ lk2,
    const float* __restrict__ slw, u16* __restrict__ attnb){
  __shared__ u16 Ksh[2][2][64 * 64];     // [buf][side][row*64 + d]
  __shared__ u16 Vsh[2][128 * 64];       // [buf][dv*64 + pos] (pos pi-permuted+swizzled)
  __shared__ float lam_s;

  int tid = threadIdx.x, w = tid >> 6, lane = tid & 63;
  int l16 = lane & 15, grp = lane >> 4;
  int bid = blockIdx.x;
  int h = bid & 7, qt = (bid >> 3) & 15, b = bid >> 7;
  int tb = b * 2048 + qt * 128;

  if (tid < 64){
    float p1 = lq1[tid] * lk1[tid], p2 = lq2[tid] * lk2[tid];
    #pragma unroll
    for (int m = 32; m >= 1; m >>= 1){ p1 += __shfl_xor(p1, m); p2 += __shfl_xor(p2, m); }
    if (tid == 0) lam_s = __expf(p1) - __expf(p2) + LAMBDA_INIT;
  }

  const u16* gK1 = Kb + (size_t)(b * 2048 + w * 16 + (lane >> 3)) * 1024 + 128 * h + (lane & 7) * 8;
  const u16* gK2 = gK1 + 64;
  const u16* gV  = Vt + (size_t)(b * 1024 + 128 * h + w * 32 + (lane >> 3)) * 2048 + (lane & 7) * 8;

  // Q fragments, 2 groups of 16 q-rows per wave
  bf16x8 q1[2][2], q2[2][2];
  #pragma unroll
  for (int g = 0; g < 2; g++){
    const u16* qr = Qb + (size_t)(tb + w * 32 + g * 16 + l16) * 1024 + 128 * h;
    q1[g][0] = *(const bf16x8*)(qr + grp * 8);
    q1[g][1] = *(const bf16x8*)(qr + 32 + grp * 8);
    q2[g][0] = *(const bf16x8*)(qr + 64 + grp * 8);
    q2[g][1] = *(const bf16x8*)(qr + 96 + grp * 8);
  }

  bf16x8 ones;
  #pragma unroll
  for (int i = 0; i < 8; i++) ones[i] = (short)0x3F80;   // bf16 1.0

#define STAGE(bb, PK1, PK2, PV) do{                         \
    async16(&Ksh[bb][0][w * 1024],       (PK1));            \
    async16(&Ksh[bb][0][w * 1024 + 512], (PK1) + 8192);     \
    async16(&Ksh[bb][1][w * 1024],       (PK2));            \
    async16(&Ksh[bb][1][w * 1024 + 512], (PK2) + 8192);     \
    async16(&Vsh[bb][w * 2048],          (PV));             \
    async16(&Vsh[bb][w * 2048 + 512],    (PV) + 16384);     \
    async16(&Vsh[bb][w * 2048 + 1024],   (PV) + 32768);     \
    async16(&Vsh[bb][w * 2048 + 1536],   (PV) + 49152);     \
  } while(0)

  STAGE(0, gK1, gK2, gV);
  gK1 += 65536; gK2 += 65536; gV += 64;
  __syncthreads();

  int xo0 = ((grp ^ (l16 & 7)) << 3);
  int xo1 = (((4 + grp) ^ (l16 & 7)) << 3);

  f32x4 O1[2][9] = {}, O2[2][9] = {};    // [g][8] = row-sum (l) accumulator

  for (int kt = 0; kt < 32; kt++){
    int cur = kt & 1;
    if (kt < 31){
      STAGE(cur ^ 1, gK1, gK2, gV);
      gK1 += 65536; gK2 += 65536; gV += 64;
      asm volatile("s_waitcnt vmcnt(8)" ::: "memory");
    } else {
      asm volatile("s_waitcnt vmcnt(0)" ::: "memory");
    }
    __builtin_amdgcn_s_barrier();

    const u16* K1p = Ksh[cur][0];
    const u16* K2p = Ksh[cur][1];
    const u16* Vp  = Vsh[cur];

    bf16x8 pbA[2][2], pbB[2][2];

    // ---- side 1: S^T = mfma(K1, Q1) for both q-groups (K frags read once) ----
    {
      f32x4 s[2][4] = {};
      #pragma unroll
      for (int n = 0; n < 4; n++){
        int rb = (n * 16 + l16) << 6;
        bf16x8 ka = *(const bf16x8*)&K1p[rb + xo0];
        bf16x8 kb = *(const bf16x8*)&K1p[rb + xo1];
        #pragma unroll
        for (int g = 0; g < 2; g++){
          s[g][n] = mfma16(ka, q1[g][0], s[g][n]);
          s[g][n] = mfma16(kb, q1[g][1], s[g][n]);
        }
      }
      #pragma unroll
      for (int g = 0; g < 2; g++){
        float p[16];
        #pragma unroll
        for (int n = 0; n < 4; n++)
          #pragma unroll
          for (int r = 0; r < 4; r++) p[n * 4 + r] = exp2_raw(s[g][n][r] - 4.0f);
        union { u32 w[4]; bf16x8 v; } u0, u1;
        #pragma unroll
        for (int j = 0; j < 4; j++){
          asm("v_cvt_pk_bf16_f32 %0, %1, %2" : "=v"(u0.w[j]) : "v"(p[2 * j]),     "v"(p[2 * j + 1]));
          asm("v_cvt_pk_bf16_f32 %0, %1, %2" : "=v"(u1.w[j]) : "v"(p[8 + 2 * j]), "v"(p[9 + 2 * j]));
        }
        pbA[g][0] = u0.v; pbA[g][1] = u1.v;
      }
    }
    // ---- side 2 ----
    {
      f32x4 s[2][4] = {};
      #pragma unroll
      for (int n = 0; n < 4; n++){
        int rb = (n * 16 + l16) << 6;
        bf16x8 ka = *(const bf16x8*)&K2p[rb + xo0];
        bf16x8 kb = *(const bf16x8*)&K2p[rb + xo1];
        #pragma unroll
        for (int g = 0; g < 2; g++){
          s[g][n] = mfma16(ka, q2[g][0], s[g][n]);
          s[g][n] = mfma16(kb, q2[g][1], s[g][n]);
        }
      }
      #pragma unroll
      for (int g = 0; g < 2; g++){
        float p[16];
        #pragma unroll
        for (int n = 0; n < 4; n++)
          #pragma unroll
          for (int r = 0; r < 4; r++) p[n * 4 + r] = exp2_raw(s[g][n][r] - 4.0f);
        union { u32 w[4]; bf16x8 v; } u0, u1;
        #pragma unroll
        for (int j = 0; j < 4; j++){
          asm("v_cvt_pk_bf16_f32 %0, %1, %2" : "=v"(u0.w[j]) : "v"(p[2 * j]),     "v"(p[2 * j + 1]));
          asm("v_cvt_pk_bf16_f32 %0, %1, %2" : "=v"(u1.w[j]) : "v"(p[8 + 2 * j]), "v"(p[9 + 2 * j]));
        }
        pbB[g][0] = u0.v; pbB[g][1] = u1.v;
      }
    }

    // ---- O^T += mfma(V^T, P^T): each V frag feeds 4 MFMAs (2 sides x 2 groups) ----
    #pragma unroll
    for (int kk = 0; kk < 2; kk++){
      int xo = kk ? xo1 : xo0;
      #pragma unroll
      for (int n = 0; n < 8; n++){
        bf16x8 av = *(const bf16x8*)&Vp[((n * 16 + l16) << 6) + xo];
        #pragma unroll
        for (int g = 0; g < 2; g++){
          O1[g][n] = mfma16(av, pbA[g][kk], O1[g][n]);
          O2[g][n] = mfma16(av, pbB[g][kk], O2[g][n]);
        }
      }
      #pragma unroll
      for (int g = 0; g < 2; g++){
        O1[g][8] = mfma16(ones, pbA[g][kk], O1[g][8]);
        O2[g][8] = mfma16(ones, pbB[g][kk], O2[g][8]);
      }
    }

    if (kt < 31){
      asm volatile("s_waitcnt lgkmcnt(0)" ::: "memory");
      __builtin_amdgcn_s_barrier();
    }
  }
#undef STAGE

  // epilogue: combine, RMSNorm(128), affine, write — per q-group
  float lam = lam_s;
  #pragma unroll
  for (int g = 0; g < 2; g++){
    float i1 = 1.f / O1[g][8][0], i2 = lam / O2[g][8][0];
    float x[8][4], ss = 0.f;
    #pragma unroll
    for (int n = 0; n < 8; n++)
      #pragma unroll
      for (int r = 0; r < 4; r++){
        float v = O1[g][n][r] * i1 - O2[g][n][r] * i2;
        x[n][r] = v; ss += v * v;
      }
    ss += __shfl_xor(ss, 16);
    ss += __shfl_xor(ss, 32);
    float ri = rsqrtf(ss * (1.f / 128.f) + 1e-5f);
    int row = tb + w * 32 + g * 16 + l16;
    #pragma unroll
    for (int n = 0; n < 8; n++){
      float4 sw = *(const float4*)&slw[n * 16 + grp * 4];
      ushort4 o;
      o.x = f2b(x[n][0] * ri * sw.x * ONE_MINUS_LI);
      o.y = f2b(x[n][1] * ri * sw.y * ONE_MINUS_LI);
      o.z = f2b(x[n][2] * ri * sw.z * ONE_MINUS_LI);
      o.w = f2b(x[n][3] * ri * sw.w * ONE_MINUS_LI);
      *(ushort4*)&attnb[(size_t)row * 1024 + h * 128 + n * 16 + grp * 4] = o;
    }
  }
}

// ---------------- host launcher ----------------
extern "C" void kernel_launch(void* const* d_in, const int* in_sizes, int n_in,
                              void* d_out, int out_size, void* d_ws, size_t ws_size,
                              hipStream_t stream){
  const float* query = (const float*)d_in[0];
  const float* Wq = (const float*)d_in[1];
  const float* Wk = (const float*)d_in[2];
  const float* Wv = (const float*)d_in[3];
  const float* Wo = (const float*)d_in[4];
  const float* lq1 = (const float*)d_in[5];
  const float* lk1 = (const float*)d_in[6];
  const float* lq2 = (const float*)d_in[7];
  const float* lk2 = (const float*)d_in[8];
  const float* slw = (const float*)d_in[9];

  char* ws = (char*)d_ws;
  u16* Xbf   = (u16*)(ws + 0);          // 8 MB  4096x1024 bf16
  u16* Wqkvt = (u16*)(ws + 8388608);    // 6 MB  3072x1024 (n-major)
  u16* Wot   = (u16*)(ws + 14680064);   // 2 MB  1024x1024 (n-major)
  u16* Qbuf  = (u16*)(ws + 16777216);   // 8 MB  (scaled by 0.125*log2e)
  u16* Kbuf  = (u16*)(ws + 25165824);   // 8 MB  (chunk-swizzled)
  u16* Vbuf  = (u16*)(ws + 33554432);   // 8 MB  token-major (coalesced GEMM write)
  u16* Vtr   = (u16*)(ws + 41943040);   // 8 MB  [b][dv][s] (pi-permuted + swizzled)
  u16* Attn  = (u16*)(ws + 50331648);   // 8 MB

  cvt_kernel<<<4096, 256, 0, stream>>>((const float4*)query, (ushort4*)Xbf, 1048576);
  wtrans<<<dim3(32, 32, 4), dim3(32, 8), 0, stream>>>(Wq, Wk, Wv, Wo, Wqkvt, Wot);

  // fused QKV projection: 4096 x 3072 x 1024
  gemm_async<128, 1><<<768, 256, 0, stream>>>(Xbf, Wqkvt, nullptr, Qbuf, Kbuf, Vbuf,
                                              4096, 3072, 1024, 32);

  // V -> [b][dv][s] with pi-permute + chunk swizzle (coalesced both sides)
  transpose_bf16<1><<<dim3(32, 64, 2), dim3(32, 8), 0, stream>>>(Vbuf, Vtr, 2048, 1024);

  diff_attn<<<256, 256, 0, stream>>>(Qbuf, Kbuf, Vtr, lq1, lk1, lq2, lk2, slw, Attn);

  // output projection -> fp32
  gemm_async<64, 0><<<512, 256, 0, stream>>>(Attn, Wot, (float*)d_out,
                                             nullptr, nullptr, nullptr,
                                             4096, 1024, 1024, 32);
}

// Round 9
// 157.634 us; speedup vs baseline: 1.0675x; 1.0675x over previous
//
#include <hip/hip_runtime.h>

typedef __attribute__((ext_vector_type(4))) float f32x4;
typedef __attribute__((ext_vector_type(8))) short bf16x8;
typedef unsigned short u16;
typedef unsigned int u32;

#define LAMBDA_INIT 0.7836057665311429f
#define ONE_MINUS_LI 0.2163942334688571f
#define QSCALE_LOG2 0.1803368801111137f   // 0.125 * log2(e)

__device__ __forceinline__ u16 f2b(float f){
  union { float f; unsigned u; } v; v.f = f;
  unsigned r = v.u + 0x7fff + ((v.u >> 16) & 1);   // RNE
  return (u16)(r >> 16);
}

__device__ __forceinline__ float b2f(u16 u){
  union { u32 i; float f; } v; v.i = (u32)u << 16; return v.f;
}

__device__ __forceinline__ f32x4 mfma16(bf16x8 a, bf16x8 b, f32x4 c){
  return __builtin_amdgcn_mfma_f32_16x16x32_bf16(a, b, c, 0, 0, 0);
}

// raw v_exp_f32 (2^x) — avoids OCML denorm-fixup libcall.
// NOTE: input must be a compiler-generated VALU result, NOT a raw MFMA dest
// (round-6 failure: asm reading MFMA dest directly -> hazard/garbage).
__device__ __forceinline__ float exp2_raw(float x){
  float r;
  asm("v_exp_f32 %0, %1" : "=v"(r) : "v"(x));
  return r;
}

// async global->LDS, 16B per lane; LDS dest = wave-uniform base + lane*16
__device__ __forceinline__ void async16(void* lds, const void* g){
  __builtin_amdgcn_global_load_lds((const __attribute__((address_space(1))) void*)g,
                                   (__attribute__((address_space(3))) void*)lds, 16, 0, 0);
}

// ---------------- convert fp32 -> bf16 (vectorized) ----------------
__global__ void cvt_kernel(const float4* __restrict__ in, ushort4* __restrict__ out, int n4){
  int i = blockIdx.x * blockDim.x + threadIdx.x;
  if (i < n4){
    float4 f = in[i];
    ushort4 o; o.x = f2b(f.x); o.y = f2b(f.y); o.z = f2b(f.z); o.w = f2b(f.w);
    out[i] = o;
  }
}

// ---------------- fused 4-weight transpose fp32[1024][1024] -> bf16[col][row] ----------------
__global__ void wtrans(const float* __restrict__ Wq, const float* __restrict__ Wk,
                       const float* __restrict__ Wv, const float* __restrict__ Wo,
                       u16* __restrict__ Wqkvt, u16* __restrict__ Wot){
  __shared__ float t[32][33];
  int z = blockIdx.z;
  const float* in = (z == 0) ? Wq : (z == 1) ? Wk : (z == 2) ? Wv : Wo;
  u16* out = (z < 3) ? (Wqkvt + (size_t)z * 1048576) : Wot;
  int c0 = blockIdx.x * 32, r0 = blockIdx.y * 32;
  int tx = threadIdx.x, ty = threadIdx.y;
  for (int i = 0; i < 32; i += 8) t[ty + i][tx] = in[(size_t)(r0 + ty + i) * 1024 + c0 + tx];
  __syncthreads();
  for (int i = 0; i < 32; i += 8) out[(size_t)(c0 + ty + i) * 1024 + r0 + tx] = f2b(t[tx][ty + i]);
}

// -------- transpose bf16[R][C] -> bf16[C][R], batched z --------
// PERM: key-tile permutation pi within each 64-chunk of the output row
// (pi(k)=32*(n>>1)+8*g+4*(n&1)+r for k=16n+4g+r) THEN the 8-elem XOR chunk swizzle.
template<int PERM>
__global__ void transpose_bf16(const u16* __restrict__ in, u16* __restrict__ out, int R, int C){
  __shared__ u16 t[32][34];
  int c0 = blockIdx.x * 32, r0 = blockIdx.y * 32;
  size_t boff = (size_t)blockIdx.z * R * C;
  int tx = threadIdx.x, ty = threadIdx.y;
  for (int i = 0; i < 32; i += 8) t[ty + i][tx] = in[boff + (size_t)(r0 + ty + i) * C + c0 + tx];
  __syncthreads();
  for (int i = 0; i < 32; i += 8){
    int dv = c0 + ty + i, s = r0 + tx;
    int sx;
    if (PERM){
      int sl = s & 63;
      int n = sl >> 4, g = (sl >> 2) & 3, r = sl & 3;
      int pos = (s & ~63) | ((n >> 1) << 5) | (g << 3) | ((n & 1) << 2) | r;
      sx = (pos & ~63) | ((((pos >> 3) & 7) ^ (dv & 7)) << 3) | (pos & 7);
    } else sx = s;
    out[boff + (size_t)dv * R + sx] = t[tx][ty + i];
  }
}

// ---------------- async double-buffered GEMM: C(MxN) = A * Bt^T ----------------
template<int BN, int EPI>
__global__ __launch_bounds__(256, 2) void gemm_async(
    const u16* __restrict__ A, const u16* __restrict__ Bt, float* __restrict__ Cp,
    u16* __restrict__ Qo, u16* __restrict__ Ko, u16* __restrict__ Vo,
    int M, int N, int K, int gm){
  constexpr int BCH = BN / 32;              // B 16B-chunks per thread per K-step
  __shared__ u16 As[2][128 * 64];
  __shared__ u16 Bs[2][BN * 64];
  int tid = threadIdx.x, w = tid >> 6, lane = tid & 63;
  int l16 = lane & 15, grp = lane >> 4;
  int wr = w >> 1, wc = w & 1;
  int nwg = gridDim.x, bid = blockIdx.x;
  int idx = (bid & 7) * (nwg >> 3) + (bid >> 3);
  int m0 = (idx & (gm - 1)) * 128, n0 = (idx / gm) * BN;

  int sr = lane >> 3;                        // == row&7 for every staged chunk
  int sc = ((lane & 7) ^ sr) << 3;           // inverse-swizzled source col (elems)
  const u16* pA = A  + (size_t)(m0 + w * 8 + sr) * K + sc;
  const u16* pB = Bt + (size_t)(n0 + w * 8 + sr) * K + sc;

  f32x4 acc[4][BN / 32] = {};

#define STAGEG(bb, k0) do{                                             \
    _Pragma("unroll")                                                  \
    for (int i = 0; i < 4; i++)                                        \
      async16(&As[bb][i * 2048 + w * 512], pA + (k0) + (size_t)i * 32 * K); \
    _Pragma("unroll")                                                  \
    for (int i = 0; i < BCH; i++)                                      \
      async16(&Bs[bb][i * 2048 + w * 512], pB + (k0) + (size_t)i * 32 * K); \
  } while(0)

  STAGEG(0, 0);
  int niter = K >> 6;
  for (int kt = 0; kt < niter; kt++){
    int cur = kt & 1;
    if (kt < niter - 1){
      STAGEG(cur ^ 1, (kt + 1) << 6);
      if constexpr (BN == 128) asm volatile("s_waitcnt vmcnt(8)" ::: "memory");
      else                     asm volatile("s_waitcnt vmcnt(6)" ::: "memory");
    } else {
      asm volatile("s_waitcnt vmcnt(0)" ::: "memory");
    }
    __builtin_amdgcn_s_barrier();

    const u16* Ap = As[cur];
    const u16* Bp = Bs[cur];
    #pragma unroll
    for (int kk = 0; kk < 2; kk++){
      bf16x8 a[4], b[BN / 32];
      #pragma unroll
      for (int m = 0; m < 4; m++){
        int r = wr * 64 + m * 16 + l16;
        a[m] = *(const bf16x8*)&Ap[r * 64 + (((kk * 4 + grp) ^ (r & 7)) << 3)];
      }
      #pragma unroll
      for (int n = 0; n < BCH; n++){
        int r = wc * (BN / 2) + n * 16 + l16;
        b[n] = *(const bf16x8*)&Bp[r * 64 + (((kk * 4 + grp) ^ (r & 7)) << 3)];
      }
      #pragma unroll
      for (int m = 0; m < 4; m++)
        #pragma unroll
        for (int n = 0; n < BCH; n++)
          acc[m][n] = mfma16(a[m], b[n], acc[m][n]);
    }
    if (kt < niter - 1){
      asm volatile("s_waitcnt lgkmcnt(0)" ::: "memory");
      __builtin_amdgcn_s_barrier();
    }
  }
#undef STAGEG

  if constexpr (EPI == 0){
    #pragma unroll
    for (int m = 0; m < 4; m++)
      #pragma unroll
      for (int n = 0; n < BCH; n++)
        #pragma unroll
        for (int r = 0; r < 4; r++)
          Cp[(size_t)(m0 + wr * 64 + m * 16 + grp * 4 + r) * N + n0 + wc * (BN / 2) + n * 16 + l16]
            = acc[m][n][r];
  } else {
    int proj = n0 >> 10;                     // block-uniform (BN=128 divides 1024)
    #pragma unroll
    for (int m = 0; m < 4; m++){
      int row = m0 + wr * 64 + m * 16 + grp * 4;
      #pragma unroll
      for (int n = 0; n < BCH; n++){
        int col = n0 + wc * (BN / 2) + n * 16 + l16;
        int cn = col & 1023;
        if (proj == 0){
          #pragma unroll
          for (int r = 0; r < 4; r++)
            Qo[(size_t)(row + r) * 1024 + cn] = f2b(acc[m][n][r] * QSCALE_LOG2);
        } else if (proj == 1){
          #pragma unroll
          for (int r = 0; r < 4; r++){
            int cs = (cn & ~63) | ((((cn >> 3) & 7) ^ ((row + r) & 7)) << 3) | (cn & 7);
            Ko[(size_t)(row + r) * 1024 + cs] = f2b(acc[m][n][r]);
          }
        } else {
          #pragma unroll
          for (int r = 0; r < 4; r++)
            Vo[(size_t)(row + r) * 1024 + cn] = f2b(acc[m][n][r]);
        }
      }
    }
  }
}

// ---------------- differential flash attention, dv-split ----------------
// grid 512 = B(2) x qt(16: 128-row tiles) x split(2: dv half) x H(8, low bits for XCD).
// 4 waves x 32 q-rows (2 groups of 16). Each block: FULL keys (l complete locally),
// PV only for its 64-dv half -> no cross-block softmax state. Writes pre-norm
// x = O1/l1 - lam*O2/l2 (bf16, disjoint cols) + per-(row,h) ssq partial; combine_rms
// applies rsqrt + affine after. Fixed-shift softmax p = 2^(s-4); l via ones-MFMA.
__global__ __launch_bounds__(256, 2) void diff_attn(
    const u16* __restrict__ Qb, const u16* __restrict__ Kb, const u16* __restrict__ Vt,
    const float* __restrict__ lq1, const float* __restrict__ lk1,
    const float* __restrict__ lq2, const float* __restrict__ lk2,
    u16* __restrict__ attnb, float* __restrict__ ssqb){
  __shared__ u16 Ksh[2][2][64 * 64];     // [buf][side][key*64 + d]
  __shared__ u16 Vsh[2][64 * 64];        // [buf][dvloc*64 + pos] (pi-permuted+swizzled)
  __shared__ float lam_s;

  int tid = threadIdx.x, w = tid >> 6, lane = tid & 63;
  int l16 = lane & 15, grp = lane >> 4;
  int bid = blockIdx.x;
  int h = bid & 7, split = (bid >> 3) & 1, qt = (bid >> 4) & 15, b = bid >> 8;
  int tb = b * 2048 + qt * 128;

  if (tid < 64){
    float p1 = lq1[tid] * lk1[tid], p2 = lq2[tid] * lk2[tid];
    #pragma unroll
    for (int m = 32; m >= 1; m >>= 1){ p1 += __shfl_xor(p1, m); p2 += __shfl_xor(p2, m); }
    if (tid == 0) lam_s = __expf(p1) - __expf(p2) + LAMBDA_INIT;
  }

  const u16* gK1 = Kb + (size_t)(b * 2048 + w * 16 + (lane >> 3)) * 1024 + 128 * h + (lane & 7) * 8;
  const u16* gK2 = gK1 + 64;
  const u16* gV  = Vt + (size_t)(b * 1024 + 128 * h + 64 * split + w * 16 + (lane >> 3)) * 2048
                      + (lane & 7) * 8;

  // Q fragments, 2 groups of 16 q-rows per wave
  bf16x8 q1[2][2], q2[2][2];
  #pragma unroll
  for (int g = 0; g < 2; g++){
    const u16* qr = Qb + (size_t)(tb + w * 32 + g * 16 + l16) * 1024 + 128 * h;
    q1[g][0] = *(const bf16x8*)(qr + grp * 8);
    q1[g][1] = *(const bf16x8*)(qr + 32 + grp * 8);
    q2[g][0] = *(const bf16x8*)(qr + 64 + grp * 8);
    q2[g][1] = *(const bf16x8*)(qr + 96 + grp * 8);
  }

  bf16x8 ones;
  #pragma unroll
  for (int i = 0; i < 8; i++) ones[i] = (short)0x3F80;   // bf16 1.0

  // 6 async16 per thread per iter: K1 x2, K2 x2, V-half x2 (wave site = 8 dv rows)
#define STAGE(bb, PK1, PK2, PV) do{                         \
    async16(&Ksh[bb][0][w * 1024],       (PK1));            \
    async16(&Ksh[bb][0][w * 1024 + 512], (PK1) + 8192);     \
    async16(&Ksh[bb][1][w * 1024],       (PK2));            \
    async16(&Ksh[bb][1][w * 1024 + 512], (PK2) + 8192);     \
    async16(&Vsh[bb][w * 1024],          (PV));             \
    async16(&Vsh[bb][w * 1024 + 512],    (PV) + 16384);     \
  } while(0)

  STAGE(0, gK1, gK2, gV);
  gK1 += 65536; gK2 += 65536; gV += 64;
  __syncthreads();                       // drains prologue loads; lam_s visible

  int xo0 = ((grp ^ (l16 & 7)) << 3);
  int xo1 = (((4 + grp) ^ (l16 & 7)) << 3);

  f32x4 O1[2][5] = {}, O2[2][5] = {};    // [g][4] = row-sum (l) accumulator

  for (int kt = 0; kt < 32; kt++){
    int cur = kt & 1;
    if (kt < 31){
      STAGE(cur ^ 1, gK1, gK2, gV);
      gK1 += 65536; gK2 += 65536; gV += 64;
      asm volatile("s_waitcnt vmcnt(6)" ::: "memory");
    } else {
      asm volatile("s_waitcnt vmcnt(0)" ::: "memory");
    }
    __builtin_amdgcn_s_barrier();

    const u16* K1p = Ksh[cur][0];
    const u16* K2p = Ksh[cur][1];
    const u16* Vp  = Vsh[cur];

    bf16x8 pbA[2][2], pbB[2][2];

    // ---- side 1: S^T = mfma(K1, Q1) for both q-groups (K frags read once) ----
    {
      f32x4 s[2][4] = {};
      #pragma unroll
      for (int n = 0; n < 4; n++){
        int rb = (n * 16 + l16) << 6;
        bf16x8 ka = *(const bf16x8*)&K1p[rb + xo0];
        bf16x8 kb = *(const bf16x8*)&K1p[rb + xo1];
        #pragma unroll
        for (int g = 0; g < 2; g++){
          s[g][n] = mfma16(ka, q1[g][0], s[g][n]);
          s[g][n] = mfma16(kb, q1[g][1], s[g][n]);
        }
      }
      #pragma unroll
      for (int g = 0; g < 2; g++){
        float p[16];
        #pragma unroll
        for (int n = 0; n < 4; n++)
          #pragma unroll
          for (int r = 0; r < 4; r++) p[n * 4 + r] = exp2_raw(s[g][n][r] - 4.0f);
        union { u32 w[4]; bf16x8 v; } u0, u1;
        #pragma unroll
        for (int j = 0; j < 4; j++){
          asm("v_cvt_pk_bf16_f32 %0, %1, %2" : "=v"(u0.w[j]) : "v"(p[2 * j]),     "v"(p[2 * j + 1]));
          asm("v_cvt_pk_bf16_f32 %0, %1, %2" : "=v"(u1.w[j]) : "v"(p[8 + 2 * j]), "v"(p[9 + 2 * j]));
        }
        pbA[g][0] = u0.v; pbA[g][1] = u1.v;
      }
    }
    // ---- side 2 ----
    {
      f32x4 s[2][4] = {};
      #pragma unroll
      for (int n = 0; n < 4; n++){
        int rb = (n * 16 + l16) << 6;
        bf16x8 ka = *(const bf16x8*)&K2p[rb + xo0];
        bf16x8 kb = *(const bf16x8*)&K2p[rb + xo1];
        #pragma unroll
        for (int g = 0; g < 2; g++){
          s[g][n] = mfma16(ka, q2[g][0], s[g][n]);
          s[g][n] = mfma16(kb, q2[g][1], s[g][n]);
        }
      }
      #pragma unroll
      for (int g = 0; g < 2; g++){
        float p[16];
        #pragma unroll
        for (int n = 0; n < 4; n++)
          #pragma unroll
          for (int r = 0; r < 4; r++) p[n * 4 + r] = exp2_raw(s[g][n][r] - 4.0f);
        union { u32 w[4]; bf16x8 v; } u0, u1;
        #pragma unroll
        for (int j = 0; j < 4; j++){
          asm("v_cvt_pk_bf16_f32 %0, %1, %2" : "=v"(u0.w[j]) : "v"(p[2 * j]),     "v"(p[2 * j + 1]));
          asm("v_cvt_pk_bf16_f32 %0, %1, %2" : "=v"(u1.w[j]) : "v"(p[8 + 2 * j]), "v"(p[9 + 2 * j]));
        }
        pbB[g][0] = u0.v; pbB[g][1] = u1.v;
      }
    }

    // ---- O^T += mfma(V^T, P^T): 64-dv half; each V frag feeds 4 MFMAs ----
    #pragma unroll
    for (int kk = 0; kk < 2; kk++){
      int xo = kk ? xo1 : xo0;
      #pragma unroll
      for (int n = 0; n < 4; n++){
        bf16x8 av = *(const bf16x8*)&Vp[((n * 16 + l16) << 6) + xo];
        #pragma unroll
        for (int g = 0; g < 2; g++){
          O1[g][n] = mfma16(av, pbA[g][kk], O1[g][n]);
          O2[g][n] = mfma16(av, pbB[g][kk], O2[g][n]);
        }
      }
      #pragma unroll
      for (int g = 0; g < 2; g++){
        O1[g][4] = mfma16(ones, pbA[g][kk], O1[g][4]);
        O2[g][4] = mfma16(ones, pbB[g][kk], O2[g][4]);
      }
    }

    if (kt < 31){
      asm volatile("s_waitcnt lgkmcnt(0)" ::: "memory");
      __builtin_amdgcn_s_barrier();
    }
  }
#undef STAGE

  // epilogue: x = O1/l1 - lam*O2/l2 (pre-norm), local ssq over this 64-dv half
  float lam = lam_s;
  #pragma unroll
  for (int g = 0; g < 2; g++){
    float i1 = 1.f / O1[g][4][0], i2 = lam / O2[g][4][0];
    float x[4][4], ss = 0.f;
    #pragma unroll
    for (int n = 0; n < 4; n++)
      #pragma unroll
      for (int r = 0; r < 4; r++){
        float v = O1[g][n][r] * i1 - O2[g][n][r] * i2;
        x[n][r] = v; ss += v * v;
      }
    ss += __shfl_xor(ss, 16);
    ss += __shfl_xor(ss, 32);
    int row = tb + w * 32 + g * 16 + l16;
    if (grp == 0) ssqb[(split * 8 + h) * 4096 + row] = ss;
    #pragma unroll
    for (int n = 0; n < 4; n++){
      ushort4 o;
      o.x = f2b(x[n][0]); o.y = f2b(x[n][1]);
      o.z = f2b(x[n][2]); o.w = f2b(x[n][3]);
      *(ushort4*)&attnb[(size_t)row * 1024 + h * 128 + split * 64 + n * 16 + grp * 4] = o;
    }
  }
}

// ---------------- combine: RMS-normalize pre-norm x in place + affine ----------------
__global__ void combine_rms(u16* __restrict__ attnb, const float* __restrict__ ssqb,
                            const float* __restrict__ slw){
  int gid = blockIdx.x * 256 + threadIdx.x;      // 524288 = 4096 rows x 128 col8-chunks
  int row = gid >> 7, c8 = (gid & 127) << 3;
  int h = c8 >> 7;
  float s0 = ssqb[h * 4096 + row];
  float s1 = ssqb[(8 + h) * 4096 + row];
  float ri = rsqrtf((s0 + s1) * (1.f / 128.f) + 1e-5f) * ONE_MINUS_LI;
  size_t base = (size_t)row * 1024 + c8;
  ushort4 a = *(ushort4*)&attnb[base];
  ushort4 bb = *(ushort4*)&attnb[base + 4];
  int cl = c8 & 127;
  float4 w0 = *(const float4*)&slw[cl];
  float4 w1 = *(const float4*)&slw[cl + 4];
  ushort4 o0, o1;
  o0.x = f2b(b2f(a.x)  * ri * w0.x); o0.y = f2b(b2f(a.y)  * ri * w0.y);
  o0.z = f2b(b2f(a.z)  * ri * w0.z); o0.w = f2b(b2f(a.w)  * ri * w0.w);
  o1.x = f2b(b2f(bb.x) * ri * w1.x); o1.y = f2b(b2f(bb.y) * ri * w1.y);
  o1.z = f2b(b2f(bb.z) * ri * w1.z); o1.w = f2b(b2f(bb.w) * ri * w1.w);
  *(ushort4*)&attnb[base] = o0;
  *(ushort4*)&attnb[base + 4] = o1;
}

// ---------------- host launcher ----------------
extern "C" void kernel_launch(void* const* d_in, const int* in_sizes, int n_in,
                              void* d_out, int out_size, void* d_ws, size_t ws_size,
                              hipStream_t stream){
  const float* query = (const float*)d_in[0];
  const float* Wq = (const float*)d_in[1];
  const float* Wk = (const float*)d_in[2];
  const float* Wv = (const float*)d_in[3];
  const float* Wo = (const float*)d_in[4];
  const float* lq1 = (const float*)d_in[5];
  const float* lk1 = (const float*)d_in[6];
  const float* lq2 = (const float*)d_in[7];
  const float* lk2 = (const float*)d_in[8];
  const float* slw = (const float*)d_in[9];

  char* ws = (char*)d_ws;
  u16* Xbf   = (u16*)(ws + 0);          // 8 MB  4096x1024 bf16
  u16* Wqkvt = (u16*)(ws + 8388608);    // 6 MB  3072x1024 (n-major)
  u16* Wot   = (u16*)(ws + 14680064);   // 2 MB  1024x1024 (n-major)
  u16* Qbuf  = (u16*)(ws + 16777216);   // 8 MB  (scaled by 0.125*log2e)
  u16* Kbuf  = (u16*)(ws + 25165824);   // 8 MB  (chunk-swizzled)
  u16* Vbuf  = (u16*)(ws + 33554432);   // 8 MB  token-major (coalesced GEMM write)
  u16* Vtr   = (u16*)(ws + 41943040);   // 8 MB  [b][dv][s] (pi-permuted + swizzled)
  u16* Attn  = (u16*)(ws + 50331648);   // 8 MB  pre-norm x -> normalized in place
  float* Ssq = (float*)(ws + 58720256); // 256 KB [2 split][8 h][4096 row]

  cvt_kernel<<<4096, 256, 0, stream>>>((const float4*)query, (ushort4*)Xbf, 1048576);
  wtrans<<<dim3(32, 32, 4), dim3(32, 8), 0, stream>>>(Wq, Wk, Wv, Wo, Wqkvt, Wot);

  // fused QKV projection: 4096 x 3072 x 1024
  gemm_async<128, 1><<<768, 256, 0, stream>>>(Xbf, Wqkvt, nullptr, Qbuf, Kbuf, Vbuf,
                                              4096, 3072, 1024, 32);

  // V -> [b][dv][s] with pi-permute + chunk swizzle (coalesced both sides)
  transpose_bf16<1><<<dim3(32, 64, 2), dim3(32, 8), 0, stream>>>(Vbuf, Vtr, 2048, 1024);

  // dv-split attention -> pre-norm x + ssq partials
  diff_attn<<<512, 256, 0, stream>>>(Qbuf, Kbuf, Vtr, lq1, lk1, lq2, lk2, Attn, Ssq);

  // RMS combine in place
  combine_rms<<<2048, 256, 0, stream>>>(Attn, Ssq, slw);

  // output projection -> fp32
  gemm_async<64, 0><<<512, 256, 0, stream>>>(Attn, Wot, (float*)d_out,
                                             nullptr, nullptr, nullptr,
                                             4096, 1024, 1024, 32);
}

// Round 10
// 138.113 us; speedup vs baseline: 1.2184x; 1.1413x over previous
//
#include <hip/hip_runtime.h>

typedef __attribute__((ext_vector_type(4))) float f32x4;
typedef __attribute__((ext_vector_type(8))) short bf16x8;
typedef unsigned short u16;
typedef unsigned int u32;

#define LAMBDA_INIT 0.7836057665311429f
#define ONE_MINUS_LI 0.2163942334688571f
#define QSCALE_LOG2 0.1803368801111137f   // 0.125 * log2(e)

__device__ __forceinline__ u16 f2b(float f){
  union { float f; unsigned u; } v; v.f = f;
  unsigned r = v.u + 0x7fff + ((v.u >> 16) & 1);   // RNE
  return (u16)(r >> 16);
}

__device__ __forceinline__ f32x4 mfma16(bf16x8 a, bf16x8 b, f32x4 c){
  return __builtin_amdgcn_mfma_f32_16x16x32_bf16(a, b, c, 0, 0, 0);
}

// raw v_exp_f32 (2^x) — avoids OCML denorm-fixup libcall.
// NOTE: input must be a compiler-generated VALU result, NOT a raw MFMA dest
// (round-6 failure: asm reading MFMA dest directly -> hazard/garbage).
__device__ __forceinline__ float exp2_raw(float x){
  float r;
  asm("v_exp_f32 %0, %1" : "=v"(r) : "v"(x));
  return r;
}

// async global->LDS, 16B per lane; LDS dest = wave-uniform base + lane*16
__device__ __forceinline__ void async16(void* lds, const void* g){
  __builtin_amdgcn_global_load_lds((const __attribute__((address_space(1))) void*)g,
                                   (__attribute__((address_space(3))) void*)lds, 16, 0, 0);
}

// ---------------- convert fp32 -> bf16 (vectorized) ----------------
__global__ void cvt_kernel(const float4* __restrict__ in, ushort4* __restrict__ out, int n4){
  int i = blockIdx.x * blockDim.x + threadIdx.x;
  if (i < n4){
    float4 f = in[i];
    ushort4 o; o.x = f2b(f.x); o.y = f2b(f.y); o.z = f2b(f.z); o.w = f2b(f.w);
    out[i] = o;
  }
}

// ---------------- fused 4-weight transpose fp32[1024][1024] -> bf16[col][row] ----------------
__global__ void wtrans(const float* __restrict__ Wq, const float* __restrict__ Wk,
                       const float* __restrict__ Wv, const float* __restrict__ Wo,
                       u16* __restrict__ Wqkvt, u16* __restrict__ Wot){
  __shared__ float t[32][33];
  int z = blockIdx.z;
  const float* in = (z == 0) ? Wq : (z == 1) ? Wk : (z == 2) ? Wv : Wo;
  u16* out = (z < 3) ? (Wqkvt + (size_t)z * 1048576) : Wot;
  int c0 = blockIdx.x * 32, r0 = blockIdx.y * 32;
  int tx = threadIdx.x, ty = threadIdx.y;
  for (int i = 0; i < 32; i += 8) t[ty + i][tx] = in[(size_t)(r0 + ty + i) * 1024 + c0 + tx];
  __syncthreads();
  for (int i = 0; i < 32; i += 8) out[(size_t)(c0 + ty + i) * 1024 + r0 + tx] = f2b(t[tx][ty + i]);
}

// -------- transpose bf16[R][C] -> bf16[C][R], batched z --------
// PERM: key-tile permutation pi within each 64-chunk of the output row
// (pi(k)=32*(n>>1)+8*g+4*(n&1)+r for k=16n+4g+r) THEN the 8-elem XOR chunk swizzle.
template<int PERM>
__global__ void transpose_bf16(const u16* __restrict__ in, u16* __restrict__ out, int R, int C){
  __shared__ u16 t[32][34];
  int c0 = blockIdx.x * 32, r0 = blockIdx.y * 32;
  size_t boff = (size_t)blockIdx.z * R * C;
  int tx = threadIdx.x, ty = threadIdx.y;
  for (int i = 0; i < 32; i += 8) t[ty + i][tx] = in[boff + (size_t)(r0 + ty + i) * C + c0 + tx];
  __syncthreads();
  for (int i = 0; i < 32; i += 8){
    int dv = c0 + ty + i, s = r0 + tx;
    int sx;
    if (PERM){
      int sl = s & 63;
      int n = sl >> 4, g = (sl >> 2) & 3, r = sl & 3;
      int pos = (s & ~63) | ((n >> 1) << 5) | (g << 3) | ((n & 1) << 2) | r;
      sx = (pos & ~63) | ((((pos >> 3) & 7) ^ (dv & 7)) << 3) | (pos & 7);
    } else sx = s;
    out[boff + (size_t)dv * R + sx] = t[tx][ty + i];
  }
}

// ---------------- async double-buffered GEMM: C(MxN) = A * Bt^T ----------------
template<int BN, int EPI>
__global__ __launch_bounds__(256, 2) void gemm_async(
    const u16* __restrict__ A, const u16* __restrict__ Bt, float* __restrict__ Cp,
    u16* __restrict__ Qo, u16* __restrict__ Ko, u16* __restrict__ Vo,
    int M, int N, int K, int gm){
  constexpr int BCH = BN / 32;              // B 16B-chunks per thread per K-step
  __shared__ u16 As[2][128 * 64];
  __shared__ u16 Bs[2][BN * 64];
  int tid = threadIdx.x, w = tid >> 6, lane = tid & 63;
  int l16 = lane & 15, grp = lane >> 4;
  int wr = w >> 1, wc = w & 1;
  int nwg = gridDim.x, bid = blockIdx.x;
  int idx = (bid & 7) * (nwg >> 3) + (bid >> 3);
  int m0 = (idx & (gm - 1)) * 128, n0 = (idx / gm) * BN;

  int sr = lane >> 3;                        // == row&7 for every staged chunk
  int sc = ((lane & 7) ^ sr) << 3;           // inverse-swizzled source col (elems)
  const u16* pA = A  + (size_t)(m0 + w * 8 + sr) * K + sc;
  const u16* pB = Bt + (size_t)(n0 + w * 8 + sr) * K + sc;

  f32x4 acc[4][BN / 32] = {};

#define STAGEG(bb, k0) do{                                             \
    _Pragma("unroll")                                                  \
    for (int i = 0; i < 4; i++)                                        \
      async16(&As[bb][i * 2048 + w * 512], pA + (k0) + (size_t)i * 32 * K); \
    _Pragma("unroll")                                                  \
    for (int i = 0; i < BCH; i++)                                      \
      async16(&Bs[bb][i * 2048 + w * 512], pB + (k0) + (size_t)i * 32 * K); \
  } while(0)

  STAGEG(0, 0);
  int niter = K >> 6;
  for (int kt = 0; kt < niter; kt++){
    int cur = kt & 1;
    if (kt < niter - 1){
      STAGEG(cur ^ 1, (kt + 1) << 6);
      if constexpr (BN == 128) asm volatile("s_waitcnt vmcnt(8)" ::: "memory");
      else                     asm volatile("s_waitcnt vmcnt(6)" ::: "memory");
    } else {
      asm volatile("s_waitcnt vmcnt(0)" ::: "memory");
    }
    __builtin_amdgcn_s_barrier();

    const u16* Ap = As[cur];
    const u16* Bp = Bs[cur];
    #pragma unroll
    for (int kk = 0; kk < 2; kk++){
      bf16x8 a[4], b[BN / 32];
      #pragma unroll
      for (int m = 0; m < 4; m++){
        int r = wr * 64 + m * 16 + l16;
        a[m] = *(const bf16x8*)&Ap[r * 64 + (((kk * 4 + grp) ^ (r & 7)) << 3)];
      }
      #pragma unroll
      for (int n = 0; n < BCH; n++){
        int r = wc * (BN / 2) + n * 16 + l16;
        b[n] = *(const bf16x8*)&Bp[r * 64 + (((kk * 4 + grp) ^ (r & 7)) << 3)];
      }
      #pragma unroll
      for (int m = 0; m < 4; m++)
        #pragma unroll
        for (int n = 0; n < BCH; n++)
          acc[m][n] = mfma16(a[m], b[n], acc[m][n]);
    }
    if (kt < niter - 1){
      asm volatile("s_waitcnt lgkmcnt(0)" ::: "memory");
      __builtin_amdgcn_s_barrier();
    }
  }
#undef STAGEG

  if constexpr (EPI == 0){
    #pragma unroll
    for (int m = 0; m < 4; m++)
      #pragma unroll
      for (int n = 0; n < BCH; n++)
        #pragma unroll
        for (int r = 0; r < 4; r++)
          Cp[(size_t)(m0 + wr * 64 + m * 16 + grp * 4 + r) * N + n0 + wc * (BN / 2) + n * 16 + l16]
            = acc[m][n][r];
  } else {
    int proj = n0 >> 10;                     // block-uniform (BN=128 divides 1024)
    #pragma unroll
    for (int m = 0; m < 4; m++){
      int row = m0 + wr * 64 + m * 16 + grp * 4;
      #pragma unroll
      for (int n = 0; n < BCH; n++){
        int col = n0 + wc * (BN / 2) + n * 16 + l16;
        int cn = col & 1023;
        if (proj == 0){
          #pragma unroll
          for (int r = 0; r < 4; r++)
            Qo[(size_t)(row + r) * 1024 + cn] = f2b(acc[m][n][r] * QSCALE_LOG2);
        } else if (proj == 1){
          #pragma unroll
          for (int r = 0; r < 4; r++){
            int cs = (cn & ~63) | ((((cn >> 3) & 7) ^ ((row + r) & 7)) << 3) | (cn & 7);
            Ko[(size_t)(row + r) * 1024 + cs] = f2b(acc[m][n][r]);
          }
        } else {
          #pragma unroll
          for (int r = 0; r < 4; r++)
            Vo[(size_t)(row + r) * 1024 + cn] = f2b(acc[m][n][r]);
        }
      }
    }
  }
}

// ---------------- differential flash attention, in-block key-split ----------------
// 512 threads = 2 teams x 4 waves. Team t processes keys [t*1024,(t+1)*1024) for the SAME
// 128 q-rows (32/wave, 2 groups of 16 -> each K/V LDS frag feeds 2x MFMAs). Each team has
// its own double-buffered K/V pipeline (2 x 64KB); barriers align (identical 16-iter loops).
// Fixed-shift softmax p = 2^(s-4) makes partials ADDITIVE: post-loop team 1 writes
// (O1,O2,l1,l2) f32 to LDS (XOR-swizzled chunks), team 0 adds, RMS-normalizes, writes.
// grid 256 -> 8 waves/CU = 2/SIMD with zero duplicated math vs round 7.
__global__ __launch_bounds__(512, 2) void diff_attn(
    const u16* __restrict__ Qb, const u16* __restrict__ Kb, const u16* __restrict__ Vt,
    const float* __restrict__ lq1, const float* __restrict__ lk1,
    const float* __restrict__ lq2, const float* __restrict__ lk2,
    const float* __restrict__ slw, u16* __restrict__ attnb){
  // LDS map (bytes): [0,131072) loop: team t at t*65536: K [buf][side][64*64]u16 (32KB)
  //                  then V [buf][128*64]u16 (32KB). Exchange (post-loop, aliases loop):
  //                  xO f32 words [0,32768): [row128][side2][chunk-swizzled 128 dv]
  //                  xl f32 words [32768,33024): [row][2]; lam at word 33024.
  __shared__ __align__(16) char smem[132352];
  u16* smemu = (u16*)smem;
  float* smemf = (float*)smem;

  int tid = threadIdx.x, w = tid >> 6, lane = tid & 63;
  int team = w >> 2, wt = w & 3;
  int l16 = lane & 15, grp = lane >> 4;
  int bid = blockIdx.x;
  int h = bid & 7, qt = (bid >> 3) & 15, b = bid >> 7;
  int tb = b * 2048 + qt * 128;

  if (tid < 64){
    float p1 = lq1[tid] * lk1[tid], p2 = lq2[tid] * lk2[tid];
    #pragma unroll
    for (int m = 32; m >= 1; m >>= 1){ p1 += __shfl_xor(p1, m); p2 += __shfl_xor(p2, m); }
    if (tid == 0) smemf[33024] = __expf(p1) - __expf(p2) + LAMBDA_INIT;
  }

  int teamU = team * 32768;              // u16 offset of this team's 64KB LDS
  const u16* gK1 = Kb + (size_t)(b * 2048 + team * 1024 + wt * 16 + (lane >> 3)) * 1024
                      + 128 * h + (lane & 7) * 8;
  const u16* gK2 = gK1 + 64;
  const u16* gV  = Vt + (size_t)(b * 1024 + 128 * h + wt * 32 + (lane >> 3)) * 2048
                      + team * 1024 + (lane & 7) * 8;

  // Q fragments, 2 groups of 16 q-rows per wave (teams load the same Q rows)
  bf16x8 q1[2][2], q2[2][2];
  #pragma unroll
  for (int g = 0; g < 2; g++){
    const u16* qr = Qb + (size_t)(tb + wt * 32 + g * 16 + l16) * 1024 + 128 * h;
    q1[g][0] = *(const bf16x8*)(qr + grp * 8);
    q1[g][1] = *(const bf16x8*)(qr + 32 + grp * 8);
    q2[g][0] = *(const bf16x8*)(qr + 64 + grp * 8);
    q2[g][1] = *(const bf16x8*)(qr + 96 + grp * 8);
  }

  bf16x8 ones;
  #pragma unroll
  for (int i = 0; i < 8; i++) ones[i] = (short)0x3F80;   // bf16 1.0

#define STAGE(bb, PK1, PK2, PV) do{                                          \
    async16(&smemu[teamU + (bb) * 8192 + wt * 1024],              (PK1));    \
    async16(&smemu[teamU + (bb) * 8192 + wt * 1024 + 512],        (PK1) + 8192); \
    async16(&smemu[teamU + (bb) * 8192 + 4096 + wt * 1024],       (PK2));    \
    async16(&smemu[teamU + (bb) * 8192 + 4096 + wt * 1024 + 512], (PK2) + 8192); \
    async16(&smemu[teamU + 16384 + (bb) * 8192 + wt * 2048],         (PV));          \
    async16(&smemu[teamU + 16384 + (bb) * 8192 + wt * 2048 + 512],   (PV) + 16384);  \
    async16(&smemu[teamU + 16384 + (bb) * 8192 + wt * 2048 + 1024],  (PV) + 32768);  \
    async16(&smemu[teamU + 16384 + (bb) * 8192 + wt * 2048 + 1536],  (PV) + 49152);  \
  } while(0)

  STAGE(0, gK1, gK2, gV);
  gK1 += 65536; gK2 += 65536; gV += 64;
  __syncthreads();                       // drains prologue loads; lam visible

  int xo0 = ((grp ^ (l16 & 7)) << 3);
  int xo1 = (((4 + grp) ^ (l16 & 7)) << 3);

  f32x4 O1[2][9] = {}, O2[2][9] = {};    // [g][8] = row-sum (l) accumulator

  for (int kt = 0; kt < 16; kt++){
    int cur = kt & 1;
    if (kt < 15){
      STAGE(cur ^ 1, gK1, gK2, gV);
      gK1 += 65536; gK2 += 65536; gV += 64;
      asm volatile("s_waitcnt vmcnt(8)" ::: "memory");
    } else {
      asm volatile("s_waitcnt vmcnt(0)" ::: "memory");
    }
    __builtin_amdgcn_s_barrier();

    const u16* K1p = smemu + teamU + cur * 8192;
    const u16* K2p = K1p + 4096;
    const u16* Vp  = smemu + teamU + 16384 + cur * 8192;

    bf16x8 pbA[2][2], pbB[2][2];

    // ---- side 1: S^T = mfma(K1, Q1) for both q-groups (K frags read once) ----
    {
      f32x4 s[2][4] = {};
      #pragma unroll
      for (int n = 0; n < 4; n++){
        int rb = (n * 16 + l16) << 6;
        bf16x8 ka = *(const bf16x8*)&K1p[rb + xo0];
        bf16x8 kb = *(const bf16x8*)&K1p[rb + xo1];
        #pragma unroll
        for (int g = 0; g < 2; g++){
          s[g][n] = mfma16(ka, q1[g][0], s[g][n]);
          s[g][n] = mfma16(kb, q1[g][1], s[g][n]);
        }
      }
      #pragma unroll
      for (int g = 0; g < 2; g++){
        float p[16];
        #pragma unroll
        for (int n = 0; n < 4; n++)
          #pragma unroll
          for (int r = 0; r < 4; r++) p[n * 4 + r] = exp2_raw(s[g][n][r] - 4.0f);
        union { u32 w[4]; bf16x8 v; } u0, u1;
        #pragma unroll
        for (int j = 0; j < 4; j++){
          asm("v_cvt_pk_bf16_f32 %0, %1, %2" : "=v"(u0.w[j]) : "v"(p[2 * j]),     "v"(p[2 * j + 1]));
          asm("v_cvt_pk_bf16_f32 %0, %1, %2" : "=v"(u1.w[j]) : "v"(p[8 + 2 * j]), "v"(p[9 + 2 * j]));
        }
        pbA[g][0] = u0.v; pbA[g][1] = u1.v;
      }
    }
    // ---- side 2 ----
    {
      f32x4 s[2][4] = {};
      #pragma unroll
      for (int n = 0; n < 4; n++){
        int rb = (n * 16 + l16) << 6;
        bf16x8 ka = *(const bf16x8*)&K2p[rb + xo0];
        bf16x8 kb = *(const bf16x8*)&K2p[rb + xo1];
        #pragma unroll
        for (int g = 0; g < 2; g++){
          s[g][n] = mfma16(ka, q2[g][0], s[g][n]);
          s[g][n] = mfma16(kb, q2[g][1], s[g][n]);
        }
      }
      #pragma unroll
      for (int g = 0; g < 2; g++){
        float p[16];
        #pragma unroll
        for (int n = 0; n < 4; n++)
          #pragma unroll
          for (int r = 0; r < 4; r++) p[n * 4 + r] = exp2_raw(s[g][n][r] - 4.0f);
        union { u32 w[4]; bf16x8 v; } u0, u1;
        #pragma unroll
        for (int j = 0; j < 4; j++){
          asm("v_cvt_pk_bf16_f32 %0, %1, %2" : "=v"(u0.w[j]) : "v"(p[2 * j]),     "v"(p[2 * j + 1]));
          asm("v_cvt_pk_bf16_f32 %0, %1, %2" : "=v"(u1.w[j]) : "v"(p[8 + 2 * j]), "v"(p[9 + 2 * j]));
        }
        pbB[g][0] = u0.v; pbB[g][1] = u1.v;
      }
    }

    // ---- O^T += mfma(V^T, P^T): each V frag feeds 4 MFMAs (2 sides x 2 groups) ----
    #pragma unroll
    for (int kk = 0; kk < 2; kk++){
      int xo = kk ? xo1 : xo0;
      #pragma unroll
      for (int n = 0; n < 8; n++){
        bf16x8 av = *(const bf16x8*)&Vp[((n * 16 + l16) << 6) + xo];
        #pragma unroll
        for (int g = 0; g < 2; g++){
          O1[g][n] = mfma16(av, pbA[g][kk], O1[g][n]);
          O2[g][n] = mfma16(av, pbB[g][kk], O2[g][n]);
        }
      }
      #pragma unroll
      for (int g = 0; g < 2; g++){
        O1[g][8] = mfma16(ones, pbA[g][kk], O1[g][8]);
        O2[g][8] = mfma16(ones, pbB[g][kk], O2[g][8]);
      }
    }

    if (kt < 15){
      asm volatile("s_waitcnt lgkmcnt(0)" ::: "memory");
      __builtin_amdgcn_s_barrier();
    }
  }
#undef STAGE

  // ---- merge: team 1 -> LDS, team 0 adds + normalizes + writes ----
  asm volatile("s_waitcnt lgkmcnt(0)" ::: "memory");
  __builtin_amdgcn_s_barrier();          // all waves done reading K/V buffers

  float lam = smemf[33024];
  if (team == 1){
    #pragma unroll
    for (int g = 0; g < 2; g++){
      int rl = wt * 32 + g * 16 + l16;         // local row 0..127
      int cx = (rl & 7) << 2;                  // chunk XOR key
      #pragma unroll
      for (int n = 0; n < 8; n++){
        int c1 = (((n * 4 + grp) ^ cx) << 2);  // swizzled chunk word offset
        *(f32x4*)&smemf[rl * 256 + c1]       = O1[g][n];
        *(f32x4*)&smemf[rl * 256 + 128 + c1] = O2[g][n];
      }
      if (grp == 0){
        smemf[32768 + rl * 2]     = O1[g][8][0];
        smemf[32768 + rl * 2 + 1] = O2[g][8][0];
      }
    }
  }
  __builtin_amdgcn_s_barrier();
  if (team == 0){
    #pragma unroll
    for (int g = 0; g < 2; g++){
      int rl = wt * 32 + g * 16 + l16;
      int cx = (rl & 7) << 2;
      float l1 = O1[g][8][0] + smemf[32768 + rl * 2];
      float l2 = O2[g][8][0] + smemf[32768 + rl * 2 + 1];
      float i1 = 1.f / l1, i2 = lam / l2;
      float x[8][4], ss = 0.f;
      #pragma unroll
      for (int n = 0; n < 8; n++){
        int c1 = (((n * 4 + grp) ^ cx) << 2);
        f32x4 ob1 = *(const f32x4*)&smemf[rl * 256 + c1];
        f32x4 ob2 = *(const f32x4*)&smemf[rl * 256 + 128 + c1];
        #pragma unroll
        for (int r = 0; r < 4; r++){
          float v = (O1[g][n][r] + ob1[r]) * i1 - (O2[g][n][r] + ob2[r]) * i2;
          x[n][r] = v; ss += v * v;
        }
      }
      ss += __shfl_xor(ss, 16);
      ss += __shfl_xor(ss, 32);
      float ri = rsqrtf(ss * (1.f / 128.f) + 1e-5f);
      int row = tb + rl;
      #pragma unroll
      for (int n = 0; n < 8; n++){
        float4 sw = *(const float4*)&slw[n * 16 + grp * 4];
        ushort4 o;
        o.x = f2b(x[n][0] * ri * sw.x * ONE_MINUS_LI);
        o.y = f2b(x[n][1] * ri * sw.y * ONE_MINUS_LI);
        o.z = f2b(x[n][2] * ri * sw.z * ONE_MINUS_LI);
        o.w = f2b(x[n][3] * ri * sw.w * ONE_MINUS_LI);
        *(ushort4*)&attnb[(size_t)row * 1024 + h * 128 + n * 16 + grp * 4] = o;
      }
    }
  }
}

// ---------------- host launcher ----------------
extern "C" void kernel_launch(void* const* d_in, const int* in_sizes, int n_in,
                              void* d_out, int out_size, void* d_ws, size_t ws_size,
                              hipStream_t stream){
  const float* query = (const float*)d_in[0];
  const float* Wq = (const float*)d_in[1];
  const float* Wk = (const float*)d_in[2];
  const float* Wv = (const float*)d_in[3];
  const float* Wo = (const float*)d_in[4];
  const float* lq1 = (const float*)d_in[5];
  const float* lk1 = (const float*)d_in[6];
  const float* lq2 = (const float*)d_in[7];
  const float* lk2 = (const float*)d_in[8];
  const float* slw = (const float*)d_in[9];

  char* ws = (char*)d_ws;
  u16* Xbf   = (u16*)(ws + 0);          // 8 MB  4096x1024 bf16
  u16* Wqkvt = (u16*)(ws + 8388608);    // 6 MB  3072x1024 (n-major)
  u16* Wot   = (u16*)(ws + 14680064);   // 2 MB  1024x1024 (n-major)
  u16* Qbuf  = (u16*)(ws + 16777216);   // 8 MB  (scaled by 0.125*log2e)
  u16* Kbuf  = (u16*)(ws + 25165824);   // 8 MB  (chunk-swizzled)
  u16* Vbuf  = (u16*)(ws + 33554432);   // 8 MB  token-major (coalesced GEMM write)
  u16* Vtr   = (u16*)(ws + 41943040);   // 8 MB  [b][dv][s] (pi-permuted + swizzled)
  u16* Attn  = (u16*)(ws + 50331648);   // 8 MB

  cvt_kernel<<<4096, 256, 0, stream>>>((const float4*)query, (ushort4*)Xbf, 1048576);
  wtrans<<<dim3(32, 32, 4), dim3(32, 8), 0, stream>>>(Wq, Wk, Wv, Wo, Wqkvt, Wot);

  // fused QKV projection: 4096 x 3072 x 1024
  gemm_async<128, 1><<<768, 256, 0, stream>>>(Xbf, Wqkvt, nullptr, Qbuf, Kbuf, Vbuf,
                                              4096, 3072, 1024, 32);

  // V -> [b][dv][s] with pi-permute + chunk swizzle (coalesced both sides)
  transpose_bf16<1><<<dim3(32, 64, 2), dim3(32, 8), 0, stream>>>(Vbuf, Vtr, 2048, 1024);

  // in-block key-split attention (512 threads, 2 teams)
  diff_attn<<<256, 512, 0, stream>>>(Qbuf, Kbuf, Vtr, lq1, lk1, lq2, lk2, slw, Attn);

  // output projection -> fp32
  gemm_async<64, 0><<<512, 256, 0, stream>>>(Attn, Wot, (float*)d_out,
                                             nullptr, nullptr, nullptr,
                                             4096, 1024, 1024, 32);
}

// Round 11
// 136.017 us; speedup vs baseline: 1.2371x; 1.0154x over previous
//
#include <hip/hip_runtime.h>

typedef __attribute__((ext_vector_type(4))) float f32x4;
typedef __attribute__((ext_vector_type(8))) short bf16x8;
typedef unsigned short u16;
typedef unsigned int u32;

#define LAMBDA_INIT 0.7836057665311429f
#define ONE_MINUS_LI 0.2163942334688571f
#define QSCALE_LOG2 0.1803368801111137f   // 0.125 * log2(e)

__device__ __forceinline__ u16 f2b(float f){
  union { float f; unsigned u; } v; v.f = f;
  unsigned r = v.u + 0x7fff + ((v.u >> 16) & 1);   // RNE
  return (u16)(r >> 16);
}

__device__ __forceinline__ f32x4 mfma16(bf16x8 a, bf16x8 b, f32x4 c){
  return __builtin_amdgcn_mfma_f32_16x16x32_bf16(a, b, c, 0, 0, 0);
}

// raw v_exp_f32 (2^x) — avoids OCML denorm-fixup libcall.
// NOTE: input must be a compiler-generated VALU result, NOT a raw MFMA dest
// (round-6 failure: asm reading MFMA dest directly -> hazard/garbage).
__device__ __forceinline__ float exp2_raw(float x){
  float r;
  asm("v_exp_f32 %0, %1" : "=v"(r) : "v"(x));
  return r;
}

// async global->LDS, 16B per lane; LDS dest = wave-uniform base + lane*16
__device__ __forceinline__ void async16(void* lds, const void* g){
  __builtin_amdgcn_global_load_lds((const __attribute__((address_space(1))) void*)g,
                                   (__attribute__((address_space(3))) void*)lds, 16, 0, 0);
}

// ---------------- convert fp32 -> bf16 (vectorized) ----------------
__global__ void cvt_kernel(const float4* __restrict__ in, ushort4* __restrict__ out, int n4){
  int i = blockIdx.x * blockDim.x + threadIdx.x;
  if (i < n4){
    float4 f = in[i];
    ushort4 o; o.x = f2b(f.x); o.y = f2b(f.y); o.z = f2b(f.z); o.w = f2b(f.w);
    out[i] = o;
  }
}

// ---------------- fused 4-weight transpose fp32[1024][1024] -> bf16[col][row] ----------------
__global__ void wtrans(const float* __restrict__ Wq, const float* __restrict__ Wk,
                       const float* __restrict__ Wv, const float* __restrict__ Wo,
                       u16* __restrict__ Wqkvt, u16* __restrict__ Wot){
  __shared__ float t[32][33];
  int z = blockIdx.z;
  const float* in = (z == 0) ? Wq : (z == 1) ? Wk : (z == 2) ? Wv : Wo;
  u16* out = (z < 3) ? (Wqkvt + (size_t)z * 1048576) : Wot;
  int c0 = blockIdx.x * 32, r0 = blockIdx.y * 32;
  int tx = threadIdx.x, ty = threadIdx.y;
  for (int i = 0; i < 32; i += 8) t[ty + i][tx] = in[(size_t)(r0 + ty + i) * 1024 + c0 + tx];
  __syncthreads();
  for (int i = 0; i < 32; i += 8) out[(size_t)(c0 + ty + i) * 1024 + r0 + tx] = f2b(t[tx][ty + i]);
}

// -------- transpose bf16[R][C] -> bf16[C][R], batched z --------
// PERM: key-tile permutation pi within each 64-chunk of the output row
// (pi(k)=32*(n>>1)+8*g+4*(n&1)+r for k=16n+4g+r) THEN the 8-elem XOR chunk swizzle.
template<int PERM>
__global__ void transpose_bf16(const u16* __restrict__ in, u16* __restrict__ out, int R, int C){
  __shared__ u16 t[32][34];
  int c0 = blockIdx.x * 32, r0 = blockIdx.y * 32;
  size_t boff = (size_t)blockIdx.z * R * C;
  int tx = threadIdx.x, ty = threadIdx.y;
  for (int i = 0; i < 32; i += 8) t[ty + i][tx] = in[boff + (size_t)(r0 + ty + i) * C + c0 + tx];
  __syncthreads();
  for (int i = 0; i < 32; i += 8){
    int dv = c0 + ty + i, s = r0 + tx;
    int sx;
    if (PERM){
      int sl = s & 63;
      int n = sl >> 4, g = (sl >> 2) & 3, r = sl & 3;
      int pos = (s & ~63) | ((n >> 1) << 5) | (g << 3) | ((n & 1) << 2) | r;
      sx = (pos & ~63) | ((((pos >> 3) & 7) ^ (dv & 7)) << 3) | (pos & 7);
    } else sx = s;
    out[boff + (size_t)dv * R + sx] = t[tx][ty + i];
  }
}

// ---------------- async double-buffered GEMM: C(MxN) = A * Bt^T ----------------
template<int BN, int EPI>
__global__ __launch_bounds__(256, 2) void gemm_async(
    const u16* __restrict__ A, const u16* __restrict__ Bt, float* __restrict__ Cp,
    u16* __restrict__ Qo, u16* __restrict__ Ko, u16* __restrict__ Vo,
    int M, int N, int K, int gm){
  constexpr int BCH = BN / 32;              // B 16B-chunks per thread per K-step
  __shared__ u16 As[2][128 * 64];
  __shared__ u16 Bs[2][BN * 64];
  int tid = threadIdx.x, w = tid >> 6, lane = tid & 63;
  int l16 = lane & 15, grp = lane >> 4;
  int wr = w >> 1, wc = w & 1;
  int nwg = gridDim.x, bid = blockIdx.x;
  int idx = (bid & 7) * (nwg >> 3) + (bid >> 3);
  int m0 = (idx & (gm - 1)) * 128, n0 = (idx / gm) * BN;

  int sr = lane >> 3;                        // == row&7 for every staged chunk
  int sc = ((lane & 7) ^ sr) << 3;           // inverse-swizzled source col (elems)
  const u16* pA = A  + (size_t)(m0 + w * 8 + sr) * K + sc;
  const u16* pB = Bt + (size_t)(n0 + w * 8 + sr) * K + sc;

  f32x4 acc[4][BN / 32] = {};

#define STAGEG(bb, k0) do{                                             \
    _Pragma("unroll")                                                  \
    for (int i = 0; i < 4; i++)                                        \
      async16(&As[bb][i * 2048 + w * 512], pA + (k0) + (size_t)i * 32 * K); \
    _Pragma("unroll")                                                  \
    for (int i = 0; i < BCH; i++)                                      \
      async16(&Bs[bb][i * 2048 + w * 512], pB + (k0) + (size_t)i * 32 * K); \
  } while(0)

  STAGEG(0, 0);
  int niter = K >> 6;
  for (int kt = 0; kt < niter; kt++){
    int cur = kt & 1;
    if (kt < niter - 1){
      STAGEG(cur ^ 1, (kt + 1) << 6);
      if constexpr (BN == 128) asm volatile("s_waitcnt vmcnt(8)" ::: "memory");
      else                     asm volatile("s_waitcnt vmcnt(6)" ::: "memory");
    } else {
      asm volatile("s_waitcnt vmcnt(0)" ::: "memory");
    }
    __builtin_amdgcn_s_barrier();

    const u16* Ap = As[cur];
    const u16* Bp = Bs[cur];
    #pragma unroll
    for (int kk = 0; kk < 2; kk++){
      bf16x8 a[4], b[BN / 32];
      #pragma unroll
      for (int m = 0; m < 4; m++){
        int r = wr * 64 + m * 16 + l16;
        a[m] = *(const bf16x8*)&Ap[r * 64 + (((kk * 4 + grp) ^ (r & 7)) << 3)];
      }
      #pragma unroll
      for (int n = 0; n < BCH; n++){
        int r = wc * (BN / 2) + n * 16 + l16;
        b[n] = *(const bf16x8*)&Bp[r * 64 + (((kk * 4 + grp) ^ (r & 7)) << 3)];
      }
      #pragma unroll
      for (int m = 0; m < 4; m++)
        #pragma unroll
        for (int n = 0; n < BCH; n++)
          acc[m][n] = mfma16(a[m], b[n], acc[m][n]);
    }
    if (kt < niter - 1){
      asm volatile("s_waitcnt lgkmcnt(0)" ::: "memory");
      __builtin_amdgcn_s_barrier();
    }
  }
#undef STAGEG

  if constexpr (EPI == 0){
    #pragma unroll
    for (int m = 0; m < 4; m++)
      #pragma unroll
      for (int n = 0; n < BCH; n++)
        #pragma unroll
        for (int r = 0; r < 4; r++)
          Cp[(size_t)(m0 + wr * 64 + m * 16 + grp * 4 + r) * N + n0 + wc * (BN / 2) + n * 16 + l16]
            = acc[m][n][r];
  } else {
    int proj = n0 >> 10;                     // block-uniform (BN=128 divides 1024)
    #pragma unroll
    for (int m = 0; m < 4; m++){
      int row = m0 + wr * 64 + m * 16 + grp * 4;
      #pragma unroll
      for (int n = 0; n < BCH; n++){
        int col = n0 + wc * (BN / 2) + n * 16 + l16;
        int cn = col & 1023;
        if (proj == 0){
          #pragma unroll
          for (int r = 0; r < 4; r++)
            Qo[(size_t)(row + r) * 1024 + cn] = f2b(acc[m][n][r] * QSCALE_LOG2);
        } else if (proj == 1){
          #pragma unroll
          for (int r = 0; r < 4; r++){
            int cs = (cn & ~63) | ((((cn >> 3) & 7) ^ ((row + r) & 7)) << 3) | (cn & 7);
            Ko[(size_t)(row + r) * 1024 + cs] = f2b(acc[m][n][r]);
          }
        } else {
          #pragma unroll
          for (int r = 0; r < 4; r++)
            Vo[(size_t)(row + r) * 1024 + cn] = f2b(acc[m][n][r]);
        }
      }
    }
  }
}

// ---------------- differential flash attention (round-7 structure + S-pipeline) ----------------
// 512 blocks x 4 waves x 16 q-rows. Scores pipelined by one K-tile: per iter,
// QK(kt+1) [MFMA] runs in the same scope as exp/cvt(kt) [VALU] (independent -> co-issued
// on separate pipes), then PV(kt). K staged early (slot free one tile ahead), V staged
// late (after PV reads), counted vmcnt(4). Fixed-shift softmax p=2^(s-4); l via ones-MFMA.
__global__ __launch_bounds__(256, 2) void diff_attn(
    const u16* __restrict__ Qb, const u16* __restrict__ Kb, const u16* __restrict__ Vt,
    const float* __restrict__ lq1, const float* __restrict__ lk1,
    const float* __restrict__ lq2, const float* __restrict__ lk2,
    const float* __restrict__ slw, u16* __restrict__ attnb){
  __shared__ u16 Ksh[2][2][64 * 64];     // [buf][side][key*64 + d]
  __shared__ u16 Vsh[2][128 * 64];       // [buf][dv*64 + pos] (pi-permuted+swizzled)
  __shared__ float lam_s;

  int tid = threadIdx.x, w = tid >> 6, lane = tid & 63;
  int l16 = lane & 15, grp = lane >> 4;
  int bid = blockIdx.x;
  int h = bid & 7, qt = (bid >> 3) & 31, b = bid >> 8;
  int tb = b * 2048 + qt * 64;

  if (tid < 64){
    float p1 = lq1[tid] * lk1[tid], p2 = lq2[tid] * lk2[tid];
    #pragma unroll
    for (int m = 32; m >= 1; m >>= 1){ p1 += __shfl_xor(p1, m); p2 += __shfl_xor(p2, m); }
    if (tid == 0) lam_s = __expf(p1) - __expf(p2) + LAMBDA_INIT;
  }

  const u16* gK1 = Kb + (size_t)(b * 2048 + w * 16 + (lane >> 3)) * 1024 + 128 * h + (lane & 7) * 8;
  const u16* gK2 = gK1 + 64;
  const u16* gV  = Vt + (size_t)(b * 1024 + 128 * h + w * 32 + (lane >> 3)) * 2048 + (lane & 7) * 8;

  bf16x8 q1[2], q2[2];
  {
    const u16* qr = Qb + (size_t)(tb + w * 16 + l16) * 1024 + 128 * h;
    q1[0] = *(const bf16x8*)(qr + grp * 8);
    q1[1] = *(const bf16x8*)(qr + 32 + grp * 8);
    q2[0] = *(const bf16x8*)(qr + 64 + grp * 8);
    q2[1] = *(const bf16x8*)(qr + 96 + grp * 8);
  }

  bf16x8 ones;
  #pragma unroll
  for (int i = 0; i < 8; i++) ones[i] = (short)0x3F80;   // bf16 1.0

#define STAGE_K(bb, PK1, PK2) do{                           \
    async16(&Ksh[bb][0][w * 1024],       (PK1));            \
    async16(&Ksh[bb][0][w * 1024 + 512], (PK1) + 8192);     \
    async16(&Ksh[bb][1][w * 1024],       (PK2));            \
    async16(&Ksh[bb][1][w * 1024 + 512], (PK2) + 8192);     \
  } while(0)
#define STAGE_V(bb, PV) do{                                 \
    async16(&Vsh[bb][w * 2048],          (PV));             \
    async16(&Vsh[bb][w * 2048 + 512],    (PV) + 16384);     \
    async16(&Vsh[bb][w * 2048 + 1024],   (PV) + 32768);     \
    async16(&Vsh[bb][w * 2048 + 1536],   (PV) + 49152);     \
  } while(0)

  int xo0 = ((grp ^ (l16 & 7)) << 3);
  int xo1 = (((4 + grp) ^ (l16 & 7)) << 3);

  // QK for tile in buf bb -> S1,S2 (zero-inited here)
#define QKCOMP(bb, S1, S2) do{                                           \
    const u16* K1p = Ksh[bb][0];                                         \
    const u16* K2p = Ksh[bb][1];                                         \
    _Pragma("unroll")                                                    \
    for (int n = 0; n < 4; n++){ S1[n] = (f32x4){0,0,0,0}; S2[n] = (f32x4){0,0,0,0}; } \
    _Pragma("unroll")                                                    \
    for (int n = 0; n < 4; n++){                                         \
      int rb = (n * 16 + l16) << 6;                                      \
      bf16x8 k1a = *(const bf16x8*)&K1p[rb + xo0];                       \
      bf16x8 k1b = *(const bf16x8*)&K1p[rb + xo1];                       \
      bf16x8 k2a = *(const bf16x8*)&K2p[rb + xo0];                       \
      bf16x8 k2b = *(const bf16x8*)&K2p[rb + xo1];                       \
      S1[n] = mfma16(k1a, q1[0], S1[n]);                                 \
      S1[n] = mfma16(k1b, q1[1], S1[n]);                                 \
      S2[n] = mfma16(k2a, q2[0], S2[n]);                                 \
      S2[n] = mfma16(k2b, q2[1], S2[n]);                                 \
    }                                                                    \
  } while(0)

  // exp/cvt: S (f32x4[4]) -> PB (bf16x8[2]), fixed shift -4
#define EXPPACK(S, PB) do{                                               \
    float p[16];                                                         \
    _Pragma("unroll")                                                    \
    for (int n = 0; n < 4; n++)                                          \
      _Pragma("unroll")                                                  \
      for (int r = 0; r < 4; r++) p[n * 4 + r] = exp2_raw(S[n][r] - 4.0f); \
    union { u32 wd[4]; bf16x8 v; } u0, u1;                               \
    _Pragma("unroll")                                                    \
    for (int j = 0; j < 4; j++){                                         \
      asm("v_cvt_pk_bf16_f32 %0, %1, %2" : "=v"(u0.wd[j]) : "v"(p[2 * j]),     "v"(p[2 * j + 1])); \
      asm("v_cvt_pk_bf16_f32 %0, %1, %2" : "=v"(u1.wd[j]) : "v"(p[8 + 2 * j]), "v"(p[9 + 2 * j])); \
    }                                                                    \
    PB[0] = u0.v; PB[1] = u1.v;                                          \
  } while(0)

  // prologue: stage tiles 0 and 1, drain, compute QK(0)
  STAGE_K(0, gK1, gK2); STAGE_V(0, gV);
  gK1 += 65536; gK2 += 65536; gV += 64;
  STAGE_K(1, gK1, gK2); STAGE_V(1, gV);
  gK1 += 65536; gK2 += 65536; gV += 64;
  __syncthreads();                       // drains all; lam_s visible

  f32x4 s1c[4], s2c[4], s1n[4], s2n[4];
  QKCOMP(0, s1c, s2c);

  f32x4 O1[9] = {}, O2[9] = {};          // [8] = row-sum (l) accumulator

  for (int kt = 0; kt < 32; kt++){
    int cur = kt & 1;
    // K(kt+2) early-staged into Ksh[cur] (K(kt) reads completed last iter)
    if (kt < 30){
      STAGE_K(cur, gK1, gK2);
      gK1 += 65536; gK2 += 65536;
      asm volatile("s_waitcnt vmcnt(4)" ::: "memory");  // K(kt+1),V(kt+1) landed
    } else {
      asm volatile("s_waitcnt vmcnt(0)" ::: "memory");
    }
    __builtin_amdgcn_s_barrier();

    // QK(kt+1) [MFMA] + exp/cvt(kt) [VALU] — independent, co-issued
    if (kt < 31) QKCOMP(cur ^ 1, s1n, s2n);
    bf16x8 pbA[2], pbB[2];
    EXPPACK(s1c, pbA);
    EXPPACK(s2c, pbB);

    // PV(kt)
    const u16* Vp = Vsh[cur];
    #pragma unroll
    for (int kk = 0; kk < 2; kk++){
      int xo = kk ? xo1 : xo0;
      #pragma unroll
      for (int n = 0; n < 8; n++){
        bf16x8 av = *(const bf16x8*)&Vp[((n * 16 + l16) << 6) + xo];
        O1[n] = mfma16(av, pbA[kk], O1[n]);
        O2[n] = mfma16(av, pbB[kk], O2[n]);
      }
      O1[8] = mfma16(ones, pbA[kk], O1[8]);
      O2[8] = mfma16(ones, pbB[kk], O2[8]);
    }

    if (kt < 31){
      asm volatile("s_waitcnt lgkmcnt(0)" ::: "memory");  // QK+PV LDS reads done
      __builtin_amdgcn_s_barrier();
      if (kt < 30){                       // V(kt+2) late-staged into Vsh[cur] (just freed)
        STAGE_V(cur, gV);
        gV += 64;
      }
      #pragma unroll
      for (int n = 0; n < 4; n++){ s1c[n] = s1n[n]; s2c[n] = s2n[n]; }
    }
  }
#undef STAGE_K
#undef STAGE_V
#undef QKCOMP
#undef EXPPACK

  // epilogue: combine, RMSNorm(128), affine, write
  float lam = lam_s;
  float i1 = 1.f / O1[8][0], i2 = lam / O2[8][0];
  float x[8][4], ss = 0.f;
  #pragma unroll
  for (int n = 0; n < 8; n++)
    #pragma unroll
    for (int r = 0; r < 4; r++){
      float v = O1[n][r] * i1 - O2[n][r] * i2;
      x[n][r] = v; ss += v * v;
    }
  ss += __shfl_xor(ss, 16);
  ss += __shfl_xor(ss, 32);
  float ri = rsqrtf(ss * (1.f / 128.f) + 1e-5f);
  int row = tb + w * 16 + l16;
  #pragma unroll
  for (int n = 0; n < 8; n++){
    float4 sw = *(const float4*)&slw[n * 16 + grp * 4];
    ushort4 o;
    o.x = f2b(x[n][0] * ri * sw.x * ONE_MINUS_LI);
    o.y = f2b(x[n][1] * ri * sw.y * ONE_MINUS_LI);
    o.z = f2b(x[n][2] * ri * sw.z * ONE_MINUS_LI);
    o.w = f2b(x[n][3] * ri * sw.w * ONE_MINUS_LI);
    *(ushort4*)&attnb[(size_t)row * 1024 + h * 128 + n * 16 + grp * 4] = o;
  }
}

// ---------------- host launcher ----------------
extern "C" void kernel_launch(void* const* d_in, const int* in_sizes, int n_in,
                              void* d_out, int out_size, void* d_ws, size_t ws_size,
                              hipStream_t stream){
  const float* query = (const float*)d_in[0];
  const float* Wq = (const float*)d_in[1];
  const float* Wk = (const float*)d_in[2];
  const float* Wv = (const float*)d_in[3];
  const float* Wo = (const float*)d_in[4];
  const float* lq1 = (const float*)d_in[5];
  const float* lk1 = (const float*)d_in[6];
  const float* lq2 = (const float*)d_in[7];
  const float* lk2 = (const float*)d_in[8];
  const float* slw = (const float*)d_in[9];

  char* ws = (char*)d_ws;
  u16* Xbf   = (u16*)(ws + 0);          // 8 MB  4096x1024 bf16
  u16* Wqkvt = (u16*)(ws + 8388608);    // 6 MB  3072x1024 (n-major)
  u16* Wot   = (u16*)(ws + 14680064);   // 2 MB  1024x1024 (n-major)
  u16* Qbuf  = (u16*)(ws + 16777216);   // 8 MB  (scaled by 0.125*log2e)
  u16* Kbuf  = (u16*)(ws + 25165824);   // 8 MB  (chunk-swizzled)
  u16* Vbuf  = (u16*)(ws + 33554432);   // 8 MB  token-major (coalesced GEMM write)
  u16* Vtr   = (u16*)(ws + 41943040);   // 8 MB  [b][dv][s] (pi-permuted + swizzled)
  u16* Attn  = (u16*)(ws + 50331648);   // 8 MB

  cvt_kernel<<<4096, 256, 0, stream>>>((const float4*)query, (ushort4*)Xbf, 1048576);
  wtrans<<<dim3(32, 32, 4), dim3(32, 8), 0, stream>>>(Wq, Wk, Wv, Wo, Wqkvt, Wot);

  // fused QKV projection: 4096 x 3072 x 1024
  gemm_async<128, 1><<<768, 256, 0, stream>>>(Xbf, Wqkvt, nullptr, Qbuf, Kbuf, Vbuf,
                                              4096, 3072, 1024, 32);

  // V -> [b][dv][s] with pi-permute + chunk swizzle (coalesced both sides)
  transpose_bf16<1><<<dim3(32, 64, 2), dim3(32, 8), 0, stream>>>(Vbuf, Vtr, 2048, 1024);

  // S-pipelined flash attention (round-7 structure)
  diff_attn<<<512, 256, 0, stream>>>(Qbuf, Kbuf, Vtr, lq1, lk1, lq2, lk2, slw, Attn);

  // output projection -> fp32
  gemm_async<64, 0><<<512, 256, 0, stream>>>(Attn, Wot, (float*)d_out,
                                             nullptr, nullptr, nullptr,
                                             4096, 1024, 1024, 32);
}

// Round 12
// 131.127 us; speedup vs baseline: 1.2833x; 1.0373x over previous
//
#include <hip/hip_runtime.h>

typedef __attribute__((ext_vector_type(4))) float f32x4;
typedef __attribute__((ext_vector_type(8))) short bf16x8;
typedef unsigned short u16;
typedef unsigned int u32;

#define LAMBDA_INIT 0.7836057665311429f
#define ONE_MINUS_LI 0.2163942334688571f
#define QSCALE_LOG2 0.1803368801111137f   // 0.125 * log2(e)

__device__ __forceinline__ u16 f2b(float f){
  union { float f; unsigned u; } v; v.f = f;
  unsigned r = v.u + 0x7fff + ((v.u >> 16) & 1);   // RNE
  return (u16)(r >> 16);
}

__device__ __forceinline__ f32x4 mfma16(bf16x8 a, bf16x8 b, f32x4 c){
  return __builtin_amdgcn_mfma_f32_16x16x32_bf16(a, b, c, 0, 0, 0);
}

// raw v_exp_f32 (2^x) — avoids OCML denorm-fixup libcall.
// NOTE: input must be a compiler-generated VALU result, NOT a raw MFMA dest
// (round-6 failure: asm reading MFMA dest directly -> hazard/garbage).
__device__ __forceinline__ float exp2_raw(float x){
  float r;
  asm("v_exp_f32 %0, %1" : "=v"(r) : "v"(x));
  return r;
}

// async global->LDS, 16B per lane; LDS dest = wave-uniform base + lane*16
__device__ __forceinline__ void async16(void* lds, const void* g){
  __builtin_amdgcn_global_load_lds((const __attribute__((address_space(1))) void*)g,
                                   (__attribute__((address_space(3))) void*)lds, 16, 0, 0);
}

// ---------------- prep: 4 weight transposes (z=0..3) + query fp32->bf16 (z=4) ----------------
__global__ void prep(const float* __restrict__ query,
                     const float* __restrict__ Wq, const float* __restrict__ Wk,
                     const float* __restrict__ Wv, const float* __restrict__ Wo,
                     u16* __restrict__ Xbf, u16* __restrict__ Wqkvt, u16* __restrict__ Wot){
  int z = blockIdx.z;
  int c0 = blockIdx.x * 32, r0 = blockIdx.y * 32;
  int tx = threadIdx.x, ty = threadIdx.y;
  if (z == 4){
    // elementwise convert, 4 row-tiles per block (rows k*1024 + r0+..)
    #pragma unroll
    for (int k = 0; k < 4; k++){
      size_t base = (size_t)(k * 1024 + r0) * 1024;
      for (int i = 0; i < 32; i += 8)
        Xbf[base + (size_t)(ty + i) * 1024 + c0 + tx] =
            f2b(query[base + (size_t)(ty + i) * 1024 + c0 + tx]);
    }
    return;
  }
  __shared__ float t[32][33];
  const float* in = (z == 0) ? Wq : (z == 1) ? Wk : (z == 2) ? Wv : Wo;
  u16* out = (z < 3) ? (Wqkvt + (size_t)z * 1048576) : Wot;
  for (int i = 0; i < 32; i += 8) t[ty + i][tx] = in[(size_t)(r0 + ty + i) * 1024 + c0 + tx];
  __syncthreads();
  for (int i = 0; i < 32; i += 8) out[(size_t)(c0 + ty + i) * 1024 + r0 + tx] = f2b(t[tx][ty + i]);
}

// -------- transpose bf16[R][C] -> bf16[C][R], batched z --------
// PERM: key-tile permutation pi within each 64-chunk of the output row
// (pi(k)=32*(n>>1)+8*g+4*(n&1)+r for k=16n+4g+r) THEN the 8-elem XOR chunk swizzle.
template<int PERM>
__global__ void transpose_bf16(const u16* __restrict__ in, u16* __restrict__ out, int R, int C){
  __shared__ u16 t[32][34];
  int c0 = blockIdx.x * 32, r0 = blockIdx.y * 32;
  size_t boff = (size_t)blockIdx.z * R * C;
  int tx = threadIdx.x, ty = threadIdx.y;
  for (int i = 0; i < 32; i += 8) t[ty + i][tx] = in[boff + (size_t)(r0 + ty + i) * C + c0 + tx];
  __syncthreads();
  for (int i = 0; i < 32; i += 8){
    int dv = c0 + ty + i, s = r0 + tx;
    int sx;
    if (PERM){
      int sl = s & 63;
      int n = sl >> 4, g = (sl >> 2) & 3, r = sl & 3;
      int pos = (s & ~63) | ((n >> 1) << 5) | (g << 3) | ((n & 1) << 2) | r;
      sx = (pos & ~63) | ((((pos >> 3) & 7) ^ (dv & 7)) << 3) | (pos & 7);
    } else sx = s;
    out[boff + (size_t)dv * R + sx] = t[tx][ty + i];
  }
}

// ---------------- async double-buffered GEMM: C(MxN) = A * Bt^T ----------------
template<int BN, int EPI>
__global__ __launch_bounds__(256, 2) void gemm_async(
    const u16* __restrict__ A, const u16* __restrict__ Bt, float* __restrict__ Cp,
    u16* __restrict__ Qo, u16* __restrict__ Ko, u16* __restrict__ Vo,
    int M, int N, int K, int gm){
  constexpr int BCH = BN / 32;              // B 16B-chunks per thread per K-step
  __shared__ u16 As[2][128 * 64];
  __shared__ u16 Bs[2][BN * 64];
  int tid = threadIdx.x, w = tid >> 6, lane = tid & 63;
  int l16 = lane & 15, grp = lane >> 4;
  int wr = w >> 1, wc = w & 1;
  int nwg = gridDim.x, bid = blockIdx.x;
  int idx = (bid & 7) * (nwg >> 3) + (bid >> 3);
  int m0 = (idx & (gm - 1)) * 128, n0 = (idx / gm) * BN;

  int sr = lane >> 3;                        // == row&7 for every staged chunk
  int sc = ((lane & 7) ^ sr) << 3;           // inverse-swizzled source col (elems)
  const u16* pA = A  + (size_t)(m0 + w * 8 + sr) * K + sc;
  const u16* pB = Bt + (size_t)(n0 + w * 8 + sr) * K + sc;

  f32x4 acc[4][BN / 32] = {};

#define STAGEG(bb, k0) do{                                             \
    _Pragma("unroll")                                                  \
    for (int i = 0; i < 4; i++)                                        \
      async16(&As[bb][i * 2048 + w * 512], pA + (k0) + (size_t)i * 32 * K); \
    _Pragma("unroll")                                                  \
    for (int i = 0; i < BCH; i++)                                      \
      async16(&Bs[bb][i * 2048 + w * 512], pB + (k0) + (size_t)i * 32 * K); \
  } while(0)

  STAGEG(0, 0);
  int niter = K >> 6;
  for (int kt = 0; kt < niter; kt++){
    int cur = kt & 1;
    if (kt < niter - 1){
      STAGEG(cur ^ 1, (kt + 1) << 6);
      if constexpr (BN == 128) asm volatile("s_waitcnt vmcnt(8)" ::: "memory");
      else                     asm volatile("s_waitcnt vmcnt(6)" ::: "memory");
    } else {
      asm volatile("s_waitcnt vmcnt(0)" ::: "memory");
    }
    __builtin_amdgcn_s_barrier();

    const u16* Ap = As[cur];
    const u16* Bp = Bs[cur];
    #pragma unroll
    for (int kk = 0; kk < 2; kk++){
      bf16x8 a[4], b[BN / 32];
      #pragma unroll
      for (int m = 0; m < 4; m++){
        int r = wr * 64 + m * 16 + l16;
        a[m] = *(const bf16x8*)&Ap[r * 64 + (((kk * 4 + grp) ^ (r & 7)) << 3)];
      }
      #pragma unroll
      for (int n = 0; n < BCH; n++){
        int r = wc * (BN / 2) + n * 16 + l16;
        b[n] = *(const bf16x8*)&Bp[r * 64 + (((kk * 4 + grp) ^ (r & 7)) << 3)];
      }
      #pragma unroll
      for (int m = 0; m < 4; m++)
        #pragma unroll
        for (int n = 0; n < BCH; n++)
          acc[m][n] = mfma16(a[m], b[n], acc[m][n]);
    }
    if (kt < niter - 1){
      asm volatile("s_waitcnt lgkmcnt(0)" ::: "memory");
      __builtin_amdgcn_s_barrier();
    }
  }
#undef STAGEG

  if constexpr (EPI == 0){
    #pragma unroll
    for (int m = 0; m < 4; m++)
      #pragma unroll
      for (int n = 0; n < BCH; n++)
        #pragma unroll
        for (int r = 0; r < 4; r++)
          Cp[(size_t)(m0 + wr * 64 + m * 16 + grp * 4 + r) * N + n0 + wc * (BN / 2) + n * 16 + l16]
            = acc[m][n][r];
  } else {
    int proj = n0 >> 10;                     // block-uniform (BN=128 divides 1024)
    #pragma unroll
    for (int m = 0; m < 4; m++){
      int row = m0 + wr * 64 + m * 16 + grp * 4;
      #pragma unroll
      for (int n = 0; n < BCH; n++){
        int col = n0 + wc * (BN / 2) + n * 16 + l16;
        int cn = col & 1023;
        if (proj == 0){
          #pragma unroll
          for (int r = 0; r < 4; r++)
            Qo[(size_t)(row + r) * 1024 + cn] = f2b(acc[m][n][r] * QSCALE_LOG2);
        } else if (proj == 1){
          #pragma unroll
          for (int r = 0; r < 4; r++){
            int cs = (cn & ~63) | ((((cn >> 3) & 7) ^ ((row + r) & 7)) << 3) | (cn & 7);
            Ko[(size_t)(row + r) * 1024 + cs] = f2b(acc[m][n][r]);
          }
        } else {
          #pragma unroll
          for (int r = 0; r < 4; r++)
            Vo[(size_t)(row + r) * 1024 + cn] = f2b(acc[m][n][r]);
        }
      }
    }
  }
}

// ---------------- differential flash attention (round-7 structure + S-pipeline) ----------------
// 512 blocks x 4 waves x 16 q-rows (8 waves/CU — the structural occupancy ceiling for
// 16 q/wave). Scores pipelined one K-tile; QK(kt+1) co-issued with exp/cvt(kt); PV wrapped
// in s_setprio(1) (T5: cross-block wave arbitration). Fixed-shift softmax p=2^(s-4);
// l via ones-MFMA column.
__global__ __launch_bounds__(256, 2) void diff_attn(
    const u16* __restrict__ Qb, const u16* __restrict__ Kb, const u16* __restrict__ Vt,
    const float* __restrict__ lq1, const float* __restrict__ lk1,
    const float* __restrict__ lq2, const float* __restrict__ lk2,
    const float* __restrict__ slw, u16* __restrict__ attnb){
  __shared__ u16 Ksh[2][2][64 * 64];     // [buf][side][key*64 + d]
  __shared__ u16 Vsh[2][128 * 64];       // [buf][dv*64 + pos] (pi-permuted+swizzled)
  __shared__ float lam_s;

  int tid = threadIdx.x, w = tid >> 6, lane = tid & 63;
  int l16 = lane & 15, grp = lane >> 4;
  int bid = blockIdx.x;
  int h = bid & 7, qt = (bid >> 3) & 31, b = bid >> 8;
  int tb = b * 2048 + qt * 64;

  if (tid < 64){
    float p1 = lq1[tid] * lk1[tid], p2 = lq2[tid] * lk2[tid];
    #pragma unroll
    for (int m = 32; m >= 1; m >>= 1){ p1 += __shfl_xor(p1, m); p2 += __shfl_xor(p2, m); }
    if (tid == 0) lam_s = __expf(p1) - __expf(p2) + LAMBDA_INIT;
  }

  const u16* gK1 = Kb + (size_t)(b * 2048 + w * 16 + (lane >> 3)) * 1024 + 128 * h + (lane & 7) * 8;
  const u16* gK2 = gK1 + 64;
  const u16* gV  = Vt + (size_t)(b * 1024 + 128 * h + w * 32 + (lane >> 3)) * 2048 + (lane & 7) * 8;

  bf16x8 q1[2], q2[2];
  {
    const u16* qr = Qb + (size_t)(tb + w * 16 + l16) * 1024 + 128 * h;
    q1[0] = *(const bf16x8*)(qr + grp * 8);
    q1[1] = *(const bf16x8*)(qr + 32 + grp * 8);
    q2[0] = *(const bf16x8*)(qr + 64 + grp * 8);
    q2[1] = *(const bf16x8*)(qr + 96 + grp * 8);
  }

  bf16x8 ones;
  #pragma unroll
  for (int i = 0; i < 8; i++) ones[i] = (short)0x3F80;   // bf16 1.0

#define STAGE_K(bb, PK1, PK2) do{                           \
    async16(&Ksh[bb][0][w * 1024],       (PK1));            \
    async16(&Ksh[bb][0][w * 1024 + 512], (PK1) + 8192);     \
    async16(&Ksh[bb][1][w * 1024],       (PK2));            \
    async16(&Ksh[bb][1][w * 1024 + 512], (PK2) + 8192);     \
  } while(0)
#define STAGE_V(bb, PV) do{                                 \
    async16(&Vsh[bb][w * 2048],          (PV));             \
    async16(&Vsh[bb][w * 2048 + 512],    (PV) + 16384);     \
    async16(&Vsh[bb][w * 2048 + 1024],   (PV) + 32768);     \
    async16(&Vsh[bb][w * 2048 + 1536],   (PV) + 49152);     \
  } while(0)

  int xo0 = ((grp ^ (l16 & 7)) << 3);
  int xo1 = (((4 + grp) ^ (l16 & 7)) << 3);

#define QKCOMP(bb, S1, S2) do{                                           \
    const u16* K1p = Ksh[bb][0];                                         \
    const u16* K2p = Ksh[bb][1];                                         \
    _Pragma("unroll")                                                    \
    for (int n = 0; n < 4; n++){ S1[n] = (f32x4){0,0,0,0}; S2[n] = (f32x4){0,0,0,0}; } \
    _Pragma("unroll")                                                    \
    for (int n = 0; n < 4; n++){                                         \
      int rb = (n * 16 + l16) << 6;                                      \
      bf16x8 k1a = *(const bf16x8*)&K1p[rb + xo0];                       \
      bf16x8 k1b = *(const bf16x8*)&K1p[rb + xo1];                       \
      bf16x8 k2a = *(const bf16x8*)&K2p[rb + xo0];                       \
      bf16x8 k2b = *(const bf16x8*)&K2p[rb + xo1];                       \
      S1[n] = mfma16(k1a, q1[0], S1[n]);                                 \
      S1[n] = mfma16(k1b, q1[1], S1[n]);                                 \
      S2[n] = mfma16(k2a, q2[0], S2[n]);                                 \
      S2[n] = mfma16(k2b, q2[1], S2[n]);                                 \
    }                                                                    \
  } while(0)

#define EXPPACK(S, PB) do{                                               \
    float p[16];                                                         \
    _Pragma("unroll")                                                    \
    for (int n = 0; n < 4; n++)                                          \
      _Pragma("unroll")                                                  \
      for (int r = 0; r < 4; r++) p[n * 4 + r] = exp2_raw(S[n][r] - 4.0f); \
    union { u32 wd[4]; bf16x8 v; } u0, u1;                               \
    _Pragma("unroll")                                                    \
    for (int j = 0; j < 4; j++){                                         \
      asm("v_cvt_pk_bf16_f32 %0, %1, %2" : "=v"(u0.wd[j]) : "v"(p[2 * j]),     "v"(p[2 * j + 1])); \
      asm("v_cvt_pk_bf16_f32 %0, %1, %2" : "=v"(u1.wd[j]) : "v"(p[8 + 2 * j]), "v"(p[9 + 2 * j])); \
    }                                                                    \
    PB[0] = u0.v; PB[1] = u1.v;                                          \
  } while(0)

  // prologue: stage tiles 0 and 1, drain, compute QK(0)
  STAGE_K(0, gK1, gK2); STAGE_V(0, gV);
  gK1 += 65536; gK2 += 65536; gV += 64;
  STAGE_K(1, gK1, gK2); STAGE_V(1, gV);
  gK1 += 65536; gK2 += 65536; gV += 64;
  __syncthreads();                       // drains all; lam_s visible

  f32x4 s1c[4], s2c[4], s1n[4], s2n[4];
  QKCOMP(0, s1c, s2c);

  f32x4 O1[9] = {}, O2[9] = {};          // [8] = row-sum (l) accumulator

  for (int kt = 0; kt < 32; kt++){
    int cur = kt & 1;
    if (kt < 30){
      STAGE_K(cur, gK1, gK2);
      gK1 += 65536; gK2 += 65536;
      asm volatile("s_waitcnt vmcnt(4)" ::: "memory");  // K(kt+1),V(kt+1) landed
    } else {
      asm volatile("s_waitcnt vmcnt(0)" ::: "memory");
    }
    __builtin_amdgcn_s_barrier();

    // QK(kt+1) [MFMA] + exp/cvt(kt) [VALU] — independent, co-issued
    if (kt < 31) QKCOMP(cur ^ 1, s1n, s2n);
    bf16x8 pbA[2], pbB[2];
    EXPPACK(s1c, pbA);
    EXPPACK(s2c, pbB);

    // PV(kt) — pure-MFMA cluster, setprio for cross-block arbitration
    const u16* Vp = Vsh[cur];
    __builtin_amdgcn_s_setprio(1);
    #pragma unroll
    for (int kk = 0; kk < 2; kk++){
      int xo = kk ? xo1 : xo0;
      #pragma unroll
      for (int n = 0; n < 8; n++){
        bf16x8 av = *(const bf16x8*)&Vp[((n * 16 + l16) << 6) + xo];
        O1[n] = mfma16(av, pbA[kk], O1[n]);
        O2[n] = mfma16(av, pbB[kk], O2[n]);
      }
      O1[8] = mfma16(ones, pbA[kk], O1[8]);
      O2[8] = mfma16(ones, pbB[kk], O2[8]);
    }
    __builtin_amdgcn_s_setprio(0);

    if (kt < 31){
      asm volatile("s_waitcnt lgkmcnt(0)" ::: "memory");  // QK+PV LDS reads done
      __builtin_amdgcn_s_barrier();
      if (kt < 30){                       // V(kt+2) late-staged into Vsh[cur] (just freed)
        STAGE_V(cur, gV);
        gV += 64;
      }
      #pragma unroll
      for (int n = 0; n < 4; n++){ s1c[n] = s1n[n]; s2c[n] = s2n[n]; }
    }
  }
#undef STAGE_K
#undef STAGE_V
#undef QKCOMP
#undef EXPPACK

  // epilogue: combine, RMSNorm(128), affine, write
  float lam = lam_s;
  float i1 = 1.f / O1[8][0], i2 = lam / O2[8][0];
  float x[8][4], ss = 0.f;
  #pragma unroll
  for (int n = 0; n < 8; n++)
    #pragma unroll
    for (int r = 0; r < 4; r++){
      float v = O1[n][r] * i1 - O2[n][r] * i2;
      x[n][r] = v; ss += v * v;
    }
  ss += __shfl_xor(ss, 16);
  ss += __shfl_xor(ss, 32);
  float ri = rsqrtf(ss * (1.f / 128.f) + 1e-5f);
  int row = tb + w * 16 + l16;
  #pragma unroll
  for (int n = 0; n < 8; n++){
    float4 sw = *(const float4*)&slw[n * 16 + grp * 4];
    ushort4 o;
    o.x = f2b(x[n][0] * ri * sw.x * ONE_MINUS_LI);
    o.y = f2b(x[n][1] * ri * sw.y * ONE_MINUS_LI);
    o.z = f2b(x[n][2] * ri * sw.z * ONE_MINUS_LI);
    o.w = f2b(x[n][3] * ri * sw.w * ONE_MINUS_LI);
    *(ushort4*)&attnb[(size_t)row * 1024 + h * 128 + n * 16 + grp * 4] = o;
  }
}

// ---------------- host launcher ----------------
extern "C" void kernel_launch(void* const* d_in, const int* in_sizes, int n_in,
                              void* d_out, int out_size, void* d_ws, size_t ws_size,
                              hipStream_t stream){
  const float* query = (const float*)d_in[0];
  const float* Wq = (const float*)d_in[1];
  const float* Wk = (const float*)d_in[2];
  const float* Wv = (const float*)d_in[3];
  const float* Wo = (const float*)d_in[4];
  const float* lq1 = (const float*)d_in[5];
  const float* lk1 = (const float*)d_in[6];
  const float* lq2 = (const float*)d_in[7];
  const float* lk2 = (const float*)d_in[8];
  const float* slw = (const float*)d_in[9];

  char* ws = (char*)d_ws;
  u16* Xbf   = (u16*)(ws + 0);          // 8 MB  4096x1024 bf16
  u16* Wqkvt = (u16*)(ws + 8388608);    // 6 MB  3072x1024 (n-major)
  u16* Wot   = (u16*)(ws + 14680064);   // 2 MB  1024x1024 (n-major)
  u16* Qbuf  = (u16*)(ws + 16777216);   // 8 MB  (scaled by 0.125*log2e)
  u16* Kbuf  = (u16*)(ws + 25165824);   // 8 MB  (chunk-swizzled)
  u16* Vbuf  = (u16*)(ws + 33554432);   // 8 MB  token-major (coalesced GEMM write)
  u16* Vtr   = (u16*)(ws + 41943040);   // 8 MB  [b][dv][s] (pi-permuted + swizzled)
  u16* Attn  = (u16*)(ws + 50331648);   // 8 MB

  // prep: weight transposes + query conversion (one launch)
  prep<<<dim3(32, 32, 5), dim3(32, 8), 0, stream>>>(query, Wq, Wk, Wv, Wo,
                                                    Xbf, Wqkvt, Wot);

  // fused QKV projection: 4096 x 3072 x 1024
  gemm_async<128, 1><<<768, 256, 0, stream>>>(Xbf, Wqkvt, nullptr, Qbuf, Kbuf, Vbuf,
                                              4096, 3072, 1024, 32);

  // V -> [b][dv][s] with pi-permute + chunk swizzle (coalesced both sides)
  transpose_bf16<1><<<dim3(32, 64, 2), dim3(32, 8), 0, stream>>>(Vbuf, Vtr, 2048, 1024);

  // S-pipelined flash attention
  diff_attn<<<512, 256, 0, stream>>>(Qbuf, Kbuf, Vtr, lq1, lk1, lq2, lk2, slw, Attn);

  // output projection -> fp32
  gemm_async<64, 0><<<512, 256, 0, stream>>>(Attn, Wot, (float*)d_out,
                                             nullptr, nullptr, nullptr,
                                             4096, 1024, 1024, 32);
}